// Round 6
// baseline (351.882 us; speedup 1.0000x reference)
//
#include <hip/hip_runtime.h>
#include <hip/hip_bf16.h>

typedef unsigned short ushort_t;
typedef short bf16x8 __attribute__((ext_vector_type(8)));
typedef ushort_t u16x8 __attribute__((ext_vector_type(8)));
typedef float f32x4 __attribute__((ext_vector_type(4)));

#define DEV static __device__ __forceinline__

DEV float bf2f(ushort_t u) { unsigned v = ((unsigned)u) << 16; float f; __builtin_memcpy(&f, &v, 4); return f; }
DEV short f2bf(float x) { __hip_bfloat16 h = __float2bfloat16(x); short s; __builtin_memcpy(&s, &h, 2); return s; }
DEV float sigm(float x) { return 1.0f / (1.0f + __expf(-x)); }

// load 8 consecutive fp32 and convert to a bf16x8 MFMA fragment
DEV bf16x8 ld8f(const float* __restrict__ p) {
    float4 a0 = *reinterpret_cast<const float4*>(p);
    float4 a1 = *reinterpret_cast<const float4*>(p + 4);
    bf16x8 t;
    t[0] = f2bf(a0.x); t[1] = f2bf(a0.y); t[2] = f2bf(a0.z); t[3] = f2bf(a0.w);
    t[4] = f2bf(a1.x); t[5] = f2bf(a1.y); t[6] = f2bf(a1.z); t[7] = f2bf(a1.w);
    return t;
}

// ---------------- K1: Ff[8192][64] = hidden@W1^T (fp32), VbT[64][8192] = (hidden@Wv^T)^T bf16
// 512 threads: waves 0-3 K-half 0, waves 4-7 K-half 1; role (wave&3) as before; LDS combine.
__global__ __launch_bounds__(512) void k_fv(const float* __restrict__ h,
        const float* __restrict__ W1, const float* __restrict__ Wv,
        float* __restrict__ Ff, ushort_t* __restrict__ VbT) {
    __shared__ float accL[4][64][9];
    int m0 = blockIdx.x * 16;
    int wave = threadIdx.x >> 6, lane = threadIdx.x & 63;
    int l16 = lane & 15, quad = lane >> 4;
    int wl = wave & 3;
    int kh = (wave >> 2) * 512;
    const float* B = (wl < 2) ? W1 : Wv;
    int cb = (wl & 1) * 32;
    f32x4 acc[2] = {};
    const float* arow = h + (long)(m0 + l16) * 1024 + kh;
    const float* brow0 = B + (long)(cb + l16) * 1024 + kh;
    const float* brow1 = B + (long)(cb + 16 + l16) * 1024 + kh;
    for (int kc = 0; kc < 512; kc += 32) {
        int ko = kc + quad * 8;
        bf16x8 af = ld8f(arow + ko);
        bf16x8 b0 = ld8f(brow0 + ko);
        bf16x8 b1v = ld8f(brow1 + ko);
        acc[0] = __builtin_amdgcn_mfma_f32_16x16x32_bf16(af, b0, acc[0], 0, 0, 0);
        acc[1] = __builtin_amdgcn_mfma_f32_16x16x32_bf16(af, b1v, acc[1], 0, 0, 0);
    }
    if (wave >= 4) {
#pragma unroll
        for (int c = 0; c < 2; c++)
#pragma unroll
            for (int rr = 0; rr < 4; rr++)
                accL[wl][lane][c * 4 + rr] = acc[c][rr];
    }
    __syncthreads();
    if (wave < 4) {
        bool isV = (wl >= 2);
#pragma unroll
        for (int c = 0; c < 2; c++)
#pragma unroll
            for (int rr = 0; rr < 4; rr++) {
                float v = acc[c][rr] + accL[wl][lane][c * 4 + rr];
                int row = m0 + quad * 4 + rr;
                int col = cb + c * 16 + l16;
                if (!isV) Ff[row * 64 + col] = v;
                else VbT[(long)col * 8192 + row] = (ushort_t)f2bf(v);
            }
    }
}

// ---------------- K2: gelu -> features -> Q,K,charge0; zero received. 256 blocks x 32 rows.
__global__ __launch_bounds__(256) void k_feat(const float* __restrict__ Ff,
        const float* __restrict__ b1, const float* __restrict__ W2, const float* __restrict__ b2,
        const float* __restrict__ Wq, const float* __restrict__ Wk,
        const float* __restrict__ Wc, const float* __restrict__ bc,
        ushort_t* __restrict__ Qb, ushort_t* __restrict__ Kb,
        float* __restrict__ charge0, float* __restrict__ received) {
    __shared__ float w2L[28 * 65], wqL[64 * 29], wkL[64 * 29], wcL[28], b2L[28];
    __shared__ float fL[4][64], featL[4][28];
    int tid = threadIdx.x;
    for (int i = tid; i < 28 * 64; i += 256) w2L[(i >> 6) * 65 + (i & 63)] = W2[i];
    for (int i = tid; i < 64 * 28; i += 256) {
        int r = i / 28, c = i - r * 28;
        wqL[r * 29 + c] = Wq[i];
        wkL[r * 29 + c] = Wk[i];
    }
    if (tid < 28) { wcL[tid] = Wc[tid]; b2L[tid] = b2[tid]; }
    __syncthreads();
    int w = tid >> 6, lane = tid & 63;
    float b1v = b1[lane];
    float bcv = bc[0];
    for (int it = 0; it < 8; it++) {
        int row = blockIdx.x * 32 + it * 4 + w;
        float x = Ff[row * 64 + lane] + b1v;
        fL[w][lane] = 0.5f * x * (1.0f + erff(x * 0.70710678118654752f));
        __syncthreads();
        if (lane < 28) {
            float s = b2L[lane];
#pragma unroll
            for (int j = 0; j < 64; j++) s += fL[w][j] * w2L[lane * 65 + j];
            featL[w][lane] = sigm(s);
        }
        __syncthreads();
        float q = 0.f, k = 0.f;
#pragma unroll
        for (int i = 0; i < 28; i++) {
            float fv = featL[w][i];
            q += fv * wqL[lane * 29 + i];
            k += fv * wkL[lane * 29 + i];
        }
        Qb[row * 64 + lane] = (ushort_t)f2bf(q * 0.125f);  // fold 1/sqrt(64)
        Kb[row * 64 + lane] = (ushort_t)f2bf(k);
        if (lane == 0) {
            float c = bcv;
#pragma unroll
            for (int i = 0; i < 28; i++) c += featL[w][i] * wcL[i];
            charge0[row] = sigm(c);
            received[row] = 0.f;
        }
        __syncthreads();
    }
}

DEV void tri_decode(int r, int& ti, int& tj) {
    int t = (int)((sqrtf(8.f * (float)r + 1.f) - 1.f) * 0.5f);
    while ((t + 1) * (t + 2) / 2 <= r) t++;
    while (t * (t + 1) / 2 > r) t--;
    ti = t;
    tj = r - t * (t + 1) / 2;
}

// ---------------- K3: compat[(b*2048+n)][m] = (Q/8)·K, causal 128x128 tiles, bf16 store
__global__ __launch_bounds__(256) void k_compat(const ushort_t* __restrict__ Qb,
                                                const ushort_t* __restrict__ Kb,
                                                ushort_t* __restrict__ compat) {
    int bid = blockIdx.x;
    int b = bid / 136, r = bid % 136, ti, tj;
    tri_decode(r, ti, tj);
    int wave = threadIdx.x >> 6, lane = threadIdx.x & 63;
    int l16 = lane & 15, quad = lane >> 4;
    int rbase = b * 2048 + ti * 128 + wave * 32;
    int cbase = b * 2048 + tj * 128;
    f32x4 acc[2][8] = {};
#pragma unroll
    for (int kc = 0; kc < 64; kc += 32) {
        int ko = kc + quad * 8;
        bf16x8 af[2], bf[8];
#pragma unroll
        for (int f = 0; f < 2; f++) af[f] = *reinterpret_cast<const bf16x8*>(Qb + (long)(rbase + f * 16 + l16) * 64 + ko);
#pragma unroll
        for (int f = 0; f < 8; f++) bf[f] = *reinterpret_cast<const bf16x8*>(Kb + (long)(cbase + f * 16 + l16) * 64 + ko);
#pragma unroll
        for (int i = 0; i < 2; i++)
#pragma unroll
            for (int j = 0; j < 8; j++)
                acc[i][j] = __builtin_amdgcn_mfma_f32_16x16x32_bf16(af[i], bf[j], acc[i][j], 0, 0, 0);
    }
    int colt = tj * 128;
#pragma unroll
    for (int i = 0; i < 2; i++)
#pragma unroll
        for (int j = 0; j < 8; j++)
#pragma unroll
            for (int rr = 0; rr < 4; rr++) {
                long rowg = rbase + i * 16 + quad * 4 + rr;
                int col = colt + j * 16 + l16;
                compat[rowg * 2048 + col] = (ushort_t)f2bf(acc[i][j][rr]);
            }
}

// ---------------- pass A: E[n][m] = exp(compat*sigma) (optionally stored bf16), Lrow = row sums
template <int T, int WE>
__global__ __launch_bounds__(256) void k_rows(const ushort_t* __restrict__ compat,
        const float4* __restrict__ charges4, const float* __restrict__ stepp,
        float* __restrict__ Lrow, ushort_t* __restrict__ Ebuf) {
    int wave = threadIdx.x >> 6, lane = threadIdx.x & 63;
    int id = blockIdx.x * 4 + wave;
    int n = id & 2047;
    int colbase = id & ~2047;
    float step = stepp[0];
    float rx = 0.f, ry = 0.f, rz = 0.f, rw = 0.f;
    if (T > 0) {
        float4 c4 = charges4[id];
        rx = step * c4.x;
        if (T > 1) ry = step * c4.y;
        if (T > 2) rz = step * c4.z;
        if (T > 3) rw = step * c4.w;
    }
    const ushort_t* crow = compat + (long)id * 2048;
    ushort_t* erow = Ebuf + (long)id * 2048;
    float S = 0.f;
    int mlim = (n & ~511) + 512;   // cover full 512-blocks so E rows are zero-padded past n
    for (int mb = lane * 8; mb < mlim; mb += 512) {
        u16x8 cv = *reinterpret_cast<const u16x8*>(crow + mb);
        u16x8 ev;
#pragma unroll
        for (int j = 0; j < 8; j++) {
            float sg = 1.f;
            if (T > 0) {
                float4 ch = charges4[colbase + mb + j];
                sg += rx * ch.x;
                if (T > 1) sg += ry * ch.y;
                if (T > 2) sg += rz * ch.z;
                if (T > 3) sg += rw * ch.w;
            }
            float e = (mb + j <= n) ? __expf(bf2f(cv[j]) * sg) : 0.f;
            S += e;
            if (WE) ev[j] = (ushort_t)f2bf(e);
        }
        if (WE) *reinterpret_cast<u16x8*>(erow + mb) = ev;
    }
#pragma unroll
    for (int off = 32; off > 0; off >>= 1) S += __shfl_down(S, off);
    if (lane == 0) Lrow[id] = fmaxf(S, 1e-30f);
}

// ---------------- pass B (bigws): received[m] += sum_n E[n][m]/L[n]; E pre-masked with zeros
__global__ __launch_bounds__(256) void k_colsum_e(const ushort_t* __restrict__ Ebuf,
        const float* __restrict__ Lrow, float* __restrict__ received) {
    __shared__ float sums[128];
    int bid = blockIdx.x;
    int b = bid / 272, rem = bid % 272;
    int z = rem & 1, r = rem >> 1, ti, tj;
    tri_decode(r, ti, tj);
    int tid = threadIdx.x;
    int ml = tid & 127, half = tid >> 7;
    int m = tj * 128 + ml;
    float acc = 0.f;
    for (int k = 0; k < 32; k++) {
        int nl = z * 64 + half + 2 * k;
        int nid = b * 2048 + ti * 128 + nl;
        float e = bf2f(Ebuf[(long)nid * 2048 + m]);
        acc += e * (1.0f / Lrow[nid]);
    }
    if (half == 0) sums[ml] = acc;
    __syncthreads();
    if (half == 1) sums[ml] += acc;
    __syncthreads();
    if (tid < 128) atomicAdd(&received[b * 2048 + tj * 128 + tid], sums[tid]);
}

// ---------------- pass B (fallback, no E buffer): recompute exp
template <int T>
__global__ __launch_bounds__(256) void k_colsum(const ushort_t* __restrict__ compat,
        const float4* __restrict__ charges4, const float* __restrict__ stepp,
        const float* __restrict__ Lrow, float* __restrict__ received) {
    __shared__ float sums[128];
    int bid = blockIdx.x;
    int b = bid / 272, rem = bid % 272;
    int z = rem & 1, r = rem >> 1, ti, tj;
    tri_decode(r, ti, tj);
    int tid = threadIdx.x;
    int ml = tid & 127, half = tid >> 7;
    int m = tj * 128 + ml;
    int mid = b * 2048 + m;
    float step = stepp[0];
    float cx = 0.f, cy = 0.f, cz = 0.f, cw = 0.f;
    if (T > 0) {
        float4 cm = charges4[mid];
        cx = step * cm.x;
        if (T > 1) cy = step * cm.y;
        if (T > 2) cz = step * cm.z;
        if (T > 3) cw = step * cm.w;
    }
    float acc = 0.f;
    bool diag = (ti == tj);
    for (int k = 0; k < 32; k++) {
        int nl = z * 64 + half + 2 * k;
        int n = ti * 128 + nl;
        int nid = b * 2048 + n;
        float Li = 1.0f / Lrow[nid];
        float sg = 1.f;
        if (T > 0) {
            float4 cn = charges4[nid];
            sg += cx * cn.x;
            if (T > 1) sg += cy * cn.y;
            if (T > 2) sg += cz * cn.z;
            if (T > 3) sg += cw * cn.w;
        }
        float c = bf2f(compat[(long)nid * 2048 + m]);
        float p = __expf(c * sg) * Li;
        if (!diag || m <= n) acc += p;
    }
    if (half == 0) sums[ml] = acc;
    __syncthreads();
    if (half == 1) sums[ml] += acc;
    __syncthreads();
    if (tid < 128) atomicAdd(&received[b * 2048 + tj * 128 + tid], sums[tid]);
}

// ---------------- charge update t (writes charges4 component T-1; re-zeroes received)
template <int T>
__global__ void k_charge(float* __restrict__ received, const float* __restrict__ charge0,
                         float4* __restrict__ charges4, const float* __restrict__ decayp) {
    int i = blockIdx.x * 256 + threadIdx.x;
    if (i >= 8192) return;
    float decay = decayp[0];
    float rcv = received[i];
    float sg = 1.0f / (1.0f + __expf(1.0f - rcv));
    float prev = (T == 1) ? charge0[i] : ((const float*)&charges4[i])[T - 2];
    ((float*)&charges4[i])[T - 1] = prev * (1.f - decay * sg);
    received[i] = 0.f;
}

// ---------------- final attention + PV, self-normalizing (512 blocks, col-split waves)
__global__ __launch_bounds__(256) void k_pv(const ushort_t* __restrict__ compat,
        const float4* __restrict__ charges4, const float* __restrict__ stepp,
        const ushort_t* __restrict__ VbT, float* __restrict__ Oacc) {
    __shared__ float accL[3][64][17];
    __shared__ float ssL[4][16];
    int bid = blockIdx.x;
    int b = bid & 3, rtile = 127 - (bid >> 2);  // big tiles dispatched first
    int r0 = rtile * 16;
    int w = threadIdx.x >> 6, lane = threadIdx.x & 63;
    int l16 = lane & 15, quad = lane >> 4;
    int rowl = r0 + l16;
    int rid = b * 2048 + rowl;
    float step = stepp[0];
    float4 c4 = charges4[rid];
    float rx = step * c4.x, ry = step * c4.y, rz = step * c4.z, rw = step * c4.w;
    const ushort_t* crow = compat + (long)rid * 2048;
    f32x4 acc[4] = {};
    float Ss = 0.f;
    int colend = r0 + 16;
    for (int kc = w * 32; kc < colend; kc += 128) {
        int mk = kc + quad * 8;
        u16x8 cv = *reinterpret_cast<const u16x8*>(crow + mk);
        const float4* chp = charges4 + b * 2048 + mk;
        bf16x8 pf;
#pragma unroll
        for (int j = 0; j < 8; j++) {
            float4 ch = chp[j];
            float sg = 1.f + rx * ch.x + ry * ch.y + rz * ch.z + rw * ch.w;
            float p = (mk + j <= rowl) ? __expf(bf2f(cv[j]) * sg) : 0.f;
            Ss += p;
            pf[j] = f2bf(p);
        }
        bf16x8 vf[4];
#pragma unroll
        for (int f = 0; f < 4; f++)
            vf[f] = *reinterpret_cast<const bf16x8*>(VbT + (long)(f * 16 + l16) * 8192 + b * 2048 + mk);
#pragma unroll
        for (int f = 0; f < 4; f++)
            acc[f] = __builtin_amdgcn_mfma_f32_16x16x32_bf16(pf, vf[f], acc[f], 0, 0, 0);
    }
    Ss += __shfl_xor(Ss, 16);
    Ss += __shfl_xor(Ss, 32);
    if (quad == 0) ssL[w][l16] = Ss;
    if (w > 0) {
#pragma unroll
        for (int f = 0; f < 4; f++)
#pragma unroll
            for (int rr = 0; rr < 4; rr++)
                accL[w - 1][lane][f * 4 + rr] = acc[f][rr];
    }
    __syncthreads();
    if (w == 0) {
#pragma unroll
        for (int f = 0; f < 4; f++)
#pragma unroll
            for (int rr = 0; rr < 4; rr++)
                acc[f][rr] += accL[0][lane][f * 4 + rr] + accL[1][lane][f * 4 + rr] + accL[2][lane][f * 4 + rr];
        float Sinv[4];
#pragma unroll
        for (int rr = 0; rr < 4; rr++) {
            int idx = quad * 4 + rr;
            float st = ssL[0][idx] + ssL[1][idx] + ssL[2][idx] + ssL[3][idx];
            Sinv[rr] = 1.f / fmaxf(st, 1e-30f);
        }
#pragma unroll
        for (int f = 0; f < 4; f++)
#pragma unroll
            for (int rr = 0; rr < 4; rr++) {
                int row = r0 + quad * 4 + rr;
                Oacc[(long)(b * 2048 + row) * 64 + f * 16 + l16] = acc[f][rr] * Sinv[rr];
            }
    }
}

// ---------------- out = (Oacc @ Wo^T) * 0.1, fp32 store
__global__ __launch_bounds__(256) void k_oproj(const float* __restrict__ Oacc,
                                               const float* __restrict__ Wo,
                                               float* __restrict__ out) {
    int mt = blockIdx.x & 63, nt = blockIdx.x >> 6;
    int wave = threadIdx.x >> 6, lane = threadIdx.x & 63;
    int wm = wave >> 1, wn = wave & 1;
    int l16 = lane & 15, quad = lane >> 4;
    int row0 = mt * 128 + wm * 64;
    int col0 = nt * 128 + wn * 64;
    f32x4 acc[4][4] = {};
#pragma unroll
    for (int kc = 0; kc < 64; kc += 32) {
        int ko = kc + quad * 8;
        bf16x8 af[4], bfm[4];
#pragma unroll
        for (int f = 0; f < 4; f++) af[f] = ld8f(Oacc + (long)(row0 + f * 16 + l16) * 64 + ko);
#pragma unroll
        for (int f = 0; f < 4; f++) bfm[f] = ld8f(Wo + (long)(col0 + f * 16 + l16) * 64 + ko);
#pragma unroll
        for (int i = 0; i < 4; i++)
#pragma unroll
            for (int j = 0; j < 4; j++)
                acc[i][j] = __builtin_amdgcn_mfma_f32_16x16x32_bf16(af[i], bfm[j], acc[i][j], 0, 0, 0);
    }
#pragma unroll
    for (int i = 0; i < 4; i++)
#pragma unroll
        for (int j = 0; j < 4; j++)
#pragma unroll
            for (int rr = 0; rr < 4; rr++) {
                long rowg = row0 + i * 16 + quad * 4 + rr;
                int colg = col0 + j * 16 + l16;
                out[rowg * 1024 + colg] = acc[i][j][rr] * 0.1f;
            }
}

extern "C" void kernel_launch(void* const* d_in, const int* in_sizes, int n_in,
                              void* d_out, int out_size, void* d_ws, size_t ws_size,
                              hipStream_t stream) {
    const float* hidden = (const float*)d_in[0];
    const float* W1 = (const float*)d_in[1];
    const float* b1 = (const float*)d_in[2];
    const float* W2 = (const float*)d_in[3];
    const float* b2 = (const float*)d_in[4];
    const float* Wq = (const float*)d_in[5];
    const float* Wk = (const float*)d_in[6];
    const float* Wc = (const float*)d_in[7];
    const float* bc = (const float*)d_in[8];
    const float* Wv = (const float*)d_in[9];
    const float* Wo = (const float*)d_in[10];
    const float* stepp = (const float*)d_in[11];
    const float* decayp = (const float*)d_in[12];

    char* ws = (char*)d_ws;
    size_t off = 0;
    auto alloc = [&](size_t bytes) {
        void* p = ws + off;
        off += (bytes + 255) & ~(size_t)255;
        return p;
    };
    ushort_t* compat = (ushort_t*)alloc(8192UL * 2048 * 2);  // 32 MiB bf16
    float* Ff = (float*)alloc(8192UL * 64 * 4);              // 2 MiB
    ushort_t* Qb = (ushort_t*)alloc(8192UL * 64 * 2);
    ushort_t* Kb = (ushort_t*)alloc(8192UL * 64 * 2);
    ushort_t* VbT = (ushort_t*)alloc(64UL * 8192 * 2);
    float* Oacc = (float*)alloc(8192UL * 64 * 4);
    float4* charges4 = (float4*)alloc(8192UL * 16);
    float* charge0 = (float*)alloc(8192UL * 4);
    float* Lrow = (float*)alloc(8192UL * 4);
    float* received = (float*)alloc(8192UL * 4);
    ushort_t* Ebuf = (ushort_t*)alloc(8192UL * 2048 * 2);    // +32 MiB (bigws only)
    bool bigws = (ws_size >= off);
    (void)in_sizes; (void)n_in; (void)out_size;

    k_fv<<<512, 512, 0, stream>>>(hidden, W1, Wv, Ff, VbT);
    k_feat<<<256, 256, 0, stream>>>(Ff, b1, W2, b2, Wq, Wk, Wc, bc, Qb, Kb, charge0, received);
    k_compat<<<544, 256, 0, stream>>>(Qb, Kb, compat);

    if (bigws) {
        k_rows<0, 1><<<2048, 256, 0, stream>>>(compat, charges4, stepp, Lrow, Ebuf);
        k_colsum_e<<<1088, 256, 0, stream>>>(Ebuf, Lrow, received);
        k_charge<1><<<32, 256, 0, stream>>>(received, charge0, charges4, decayp);

        k_rows<1, 1><<<2048, 256, 0, stream>>>(compat, charges4, stepp, Lrow, Ebuf);
        k_colsum_e<<<1088, 256, 0, stream>>>(Ebuf, Lrow, received);
        k_charge<2><<<32, 256, 0, stream>>>(received, charge0, charges4, decayp);

        k_rows<2, 1><<<2048, 256, 0, stream>>>(compat, charges4, stepp, Lrow, Ebuf);
        k_colsum_e<<<1088, 256, 0, stream>>>(Ebuf, Lrow, received);
        k_charge<3><<<32, 256, 0, stream>>>(received, charge0, charges4, decayp);

        k_rows<3, 1><<<2048, 256, 0, stream>>>(compat, charges4, stepp, Lrow, Ebuf);
        k_colsum_e<<<1088, 256, 0, stream>>>(Ebuf, Lrow, received);
        k_charge<4><<<32, 256, 0, stream>>>(received, charge0, charges4, decayp);
    } else {
        k_rows<0, 0><<<2048, 256, 0, stream>>>(compat, charges4, stepp, Lrow, Ebuf);
        k_colsum<0><<<1088, 256, 0, stream>>>(compat, charges4, stepp, Lrow, received);
        k_charge<1><<<32, 256, 0, stream>>>(received, charge0, charges4, decayp);

        k_rows<1, 0><<<2048, 256, 0, stream>>>(compat, charges4, stepp, Lrow, Ebuf);
        k_colsum<1><<<1088, 256, 0, stream>>>(compat, charges4, stepp, Lrow, received);
        k_charge<2><<<32, 256, 0, stream>>>(received, charge0, charges4, decayp);

        k_rows<2, 0><<<2048, 256, 0, stream>>>(compat, charges4, stepp, Lrow, Ebuf);
        k_colsum<2><<<1088, 256, 0, stream>>>(compat, charges4, stepp, Lrow, received);
        k_charge<3><<<32, 256, 0, stream>>>(received, charge0, charges4, decayp);

        k_rows<3, 0><<<2048, 256, 0, stream>>>(compat, charges4, stepp, Lrow, Ebuf);
        k_colsum<3><<<1088, 256, 0, stream>>>(compat, charges4, stepp, Lrow, received);
        k_charge<4><<<32, 256, 0, stream>>>(received, charge0, charges4, decayp);
    }

    k_pv<<<512, 256, 0, stream>>>(compat, charges4, stepp, VbT, Oacc);
    k_oproj<<<512, 256, 0, stream>>>(Oacc, Wo, (float*)d_out);
}

// Round 7
// 330.965 us; speedup vs baseline: 1.0632x; 1.0632x over previous
//
#include <hip/hip_runtime.h>
#include <hip/hip_bf16.h>

typedef unsigned short ushort_t;
typedef short bf16x8 __attribute__((ext_vector_type(8)));
typedef ushort_t u16x8 __attribute__((ext_vector_type(8)));
typedef float f32x4 __attribute__((ext_vector_type(4)));

#define DEV static __device__ __forceinline__

DEV float bf2f(ushort_t u) { unsigned v = ((unsigned)u) << 16; float f; __builtin_memcpy(&f, &v, 4); return f; }
DEV short f2bf(float x) { __hip_bfloat16 h = __float2bfloat16(x); short s; __builtin_memcpy(&s, &h, 2); return s; }
DEV float sigm(float x) { return 1.0f / (1.0f + __expf(-x)); }

DEV bf16x8 cvt8(float4 a0, float4 a1) {
    bf16x8 t;
    t[0] = f2bf(a0.x); t[1] = f2bf(a0.y); t[2] = f2bf(a0.z); t[3] = f2bf(a0.w);
    t[4] = f2bf(a1.x); t[5] = f2bf(a1.y); t[6] = f2bf(a1.z); t[7] = f2bf(a1.w);
    return t;
}
DEV bf16x8 ld8f(const float* __restrict__ p) {
    return cvt8(*reinterpret_cast<const float4*>(p), *reinterpret_cast<const float4*>(p + 4));
}

// ---------------- K1: Ff[8192][64] = hidden@W1^T (fp32), VbT[64][8192] = (hidden@Wv^T)^T bf16
// 4 waves: {W1,Wv} x {cols 0-31, 32-63}. K-loop batches 4x32 of loads (24 loads in flight)
// before converting + 8 MFMAs, to maximize outstanding VMEM (k_fv was in-flight-bytes-bound).
__global__ __launch_bounds__(256) void k_fv(const float* __restrict__ h,
        const float* __restrict__ W1, const float* __restrict__ Wv,
        float* __restrict__ Ff, ushort_t* __restrict__ VbT) {
    int m0 = blockIdx.x * 16;
    int wave = threadIdx.x >> 6, lane = threadIdx.x & 63;
    int l16 = lane & 15, quad = lane >> 4;
    const float* B = (wave < 2) ? W1 : Wv;
    int cb = (wave & 1) * 32;
    f32x4 acc[2] = {};
    const float* arow = h + (long)(m0 + l16) * 1024;
    const float* brow0 = B + (long)(cb + l16) * 1024;
    const float* brow1 = B + (long)(cb + 16 + l16) * 1024;
    for (int kc = 0; kc < 1024; kc += 128) {
        float4 ra[4][2], r0[4][2], r1[4][2];
#pragma unroll
        for (int u = 0; u < 4; u++) {
            int ko = kc + u * 32 + quad * 8;
            ra[u][0] = *reinterpret_cast<const float4*>(arow + ko);
            ra[u][1] = *reinterpret_cast<const float4*>(arow + ko + 4);
            r0[u][0] = *reinterpret_cast<const float4*>(brow0 + ko);
            r0[u][1] = *reinterpret_cast<const float4*>(brow0 + ko + 4);
            r1[u][0] = *reinterpret_cast<const float4*>(brow1 + ko);
            r1[u][1] = *reinterpret_cast<const float4*>(brow1 + ko + 4);
        }
#pragma unroll
        for (int u = 0; u < 4; u++) {
            bf16x8 af = cvt8(ra[u][0], ra[u][1]);
            bf16x8 b0 = cvt8(r0[u][0], r0[u][1]);
            bf16x8 b1v = cvt8(r1[u][0], r1[u][1]);
            acc[0] = __builtin_amdgcn_mfma_f32_16x16x32_bf16(af, b0, acc[0], 0, 0, 0);
            acc[1] = __builtin_amdgcn_mfma_f32_16x16x32_bf16(af, b1v, acc[1], 0, 0, 0);
        }
    }
    bool isV = (wave >= 2);
#pragma unroll
    for (int c = 0; c < 2; c++)
#pragma unroll
        for (int rr = 0; rr < 4; rr++) {
            int row = m0 + quad * 4 + rr;
            int col = cb + c * 16 + l16;
            float v = acc[c][rr];
            if (!isV) Ff[row * 64 + col] = v;
            else VbT[(long)col * 8192 + row] = (ushort_t)f2bf(v);
        }
}

// ---------------- K2: gelu -> features -> Q,K,charge0; zero received. 256 blocks x 32 rows.
__global__ __launch_bounds__(256) void k_feat(const float* __restrict__ Ff,
        const float* __restrict__ b1, const float* __restrict__ W2, const float* __restrict__ b2,
        const float* __restrict__ Wq, const float* __restrict__ Wk,
        const float* __restrict__ Wc, const float* __restrict__ bc,
        ushort_t* __restrict__ Qb, ushort_t* __restrict__ Kb,
        float* __restrict__ charge0, float* __restrict__ received) {
    __shared__ float w2L[28 * 65], wqL[64 * 29], wkL[64 * 29], wcL[28], b2L[28];
    __shared__ float fL[4][64], featL[4][28];
    int tid = threadIdx.x;
    for (int i = tid; i < 28 * 64; i += 256) w2L[(i >> 6) * 65 + (i & 63)] = W2[i];
    for (int i = tid; i < 64 * 28; i += 256) {
        int r = i / 28, c = i - r * 28;
        wqL[r * 29 + c] = Wq[i];
        wkL[r * 29 + c] = Wk[i];
    }
    if (tid < 28) { wcL[tid] = Wc[tid]; b2L[tid] = b2[tid]; }
    __syncthreads();
    int w = tid >> 6, lane = tid & 63;
    float b1v = b1[lane];
    float bcv = bc[0];
    for (int it = 0; it < 8; it++) {
        int row = blockIdx.x * 32 + it * 4 + w;
        float x = Ff[row * 64 + lane] + b1v;
        fL[w][lane] = 0.5f * x * (1.0f + erff(x * 0.70710678118654752f));
        __syncthreads();
        if (lane < 28) {
            float s = b2L[lane];
#pragma unroll
            for (int j = 0; j < 64; j++) s += fL[w][j] * w2L[lane * 65 + j];
            featL[w][lane] = sigm(s);
        }
        __syncthreads();
        float q = 0.f, k = 0.f;
#pragma unroll
        for (int i = 0; i < 28; i++) {
            float fv = featL[w][i];
            q += fv * wqL[lane * 29 + i];
            k += fv * wkL[lane * 29 + i];
        }
        Qb[row * 64 + lane] = (ushort_t)f2bf(q * 0.125f);  // fold 1/sqrt(64)
        Kb[row * 64 + lane] = (ushort_t)f2bf(k);
        if (lane == 0) {
            float c = bcv;
#pragma unroll
            for (int i = 0; i < 28; i++) c += featL[w][i] * wcL[i];
            charge0[row] = sigm(c);
            received[row] = 0.f;
        }
        __syncthreads();
    }
}

DEV void tri_decode(int r, int& ti, int& tj) {
    int t = (int)((sqrtf(8.f * (float)r + 1.f) - 1.f) * 0.5f);
    while ((t + 1) * (t + 2) / 2 <= r) t++;
    while (t * (t + 1) / 2 > r) t--;
    ti = t;
    tj = r - t * (t + 1) / 2;
}

// ---------------- K3: compat[(b*2048+n)][m] = (Q/8)·K, causal 128x128 tiles, bf16 store
__global__ __launch_bounds__(256) void k_compat(const ushort_t* __restrict__ Qb,
                                                const ushort_t* __restrict__ Kb,
                                                ushort_t* __restrict__ compat) {
    int bid = blockIdx.x;
    int b = bid / 136, r = bid % 136, ti, tj;
    tri_decode(r, ti, tj);
    int wave = threadIdx.x >> 6, lane = threadIdx.x & 63;
    int l16 = lane & 15, quad = lane >> 4;
    int rbase = b * 2048 + ti * 128 + wave * 32;
    int cbase = b * 2048 + tj * 128;
    f32x4 acc[2][8] = {};
#pragma unroll
    for (int kc = 0; kc < 64; kc += 32) {
        int ko = kc + quad * 8;
        bf16x8 af[2], bf[8];
#pragma unroll
        for (int f = 0; f < 2; f++) af[f] = *reinterpret_cast<const bf16x8*>(Qb + (long)(rbase + f * 16 + l16) * 64 + ko);
#pragma unroll
        for (int f = 0; f < 8; f++) bf[f] = *reinterpret_cast<const bf16x8*>(Kb + (long)(cbase + f * 16 + l16) * 64 + ko);
#pragma unroll
        for (int i = 0; i < 2; i++)
#pragma unroll
            for (int j = 0; j < 8; j++)
                acc[i][j] = __builtin_amdgcn_mfma_f32_16x16x32_bf16(af[i], bf[j], acc[i][j], 0, 0, 0);
    }
    int colt = tj * 128;
#pragma unroll
    for (int i = 0; i < 2; i++)
#pragma unroll
        for (int j = 0; j < 8; j++)
#pragma unroll
            for (int rr = 0; rr < 4; rr++) {
                long rowg = rbase + i * 16 + quad * 4 + rr;
                int col = colt + j * 16 + l16;
                compat[rowg * 2048 + col] = (ushort_t)f2bf(acc[i][j][rr]);
            }
}

// ---------------- pass A: Lrow[n] = sum_m<=n exp(compat*sigma).
// Block = 16 rows of one batch (big-first); wave = 4 rows sharing each column-charges load
// (amortizes 16B charges over 4 rows; 5 independent coalesced loads in flight per iter).
template <int T>
__global__ __launch_bounds__(256) void k_rowstats(const ushort_t* __restrict__ compat,
        const float4* __restrict__ charges4, const float* __restrict__ stepp,
        float* __restrict__ Lrow) {
    int bid = blockIdx.x;
    int b = bid & 3, rt = 127 - (bid >> 2);   // big tiles first
    int w = threadIdx.x >> 6, lane = threadIdx.x & 63;
    int rw0 = rt * 16 + w * 4;                // this wave's 4 rows (within batch)
    int colbase = b * 2048;
    float step = stepp[0];
    float rfx[4] = {}, rfy[4] = {}, rfz[4] = {}, rfw[4] = {};
    if (T > 0) {
#pragma unroll
        for (int r = 0; r < 4; r++) {
            float4 c4 = charges4[colbase + rw0 + r];
            rfx[r] = step * c4.x;
            if (T > 1) rfy[r] = step * c4.y;
            if (T > 2) rfz[r] = step * c4.z;
            if (T > 3) rfw[r] = step * c4.w;
        }
    }
    const ushort_t* crow0 = compat + (long)(colbase + rw0) * 2048;
    float S[4] = {0.f, 0.f, 0.f, 0.f};
    int nmax = rw0 + 3;
    for (int m = lane; m <= nmax; m += 64) {
        ushort_t cv[4];
#pragma unroll
        for (int r = 0; r < 4; r++) cv[r] = crow0[(long)r * 2048 + m];
        float sx = 0.f, sy = 0.f, sz = 0.f, sw = 0.f;
        if (T > 0) {
            float4 ch = charges4[colbase + m];
            sx = ch.x; sy = ch.y; sz = ch.z; sw = ch.w;
        }
#pragma unroll
        for (int r = 0; r < 4; r++) {
            float sg = 1.f;
            if (T > 0) sg += rfx[r] * sx;
            if (T > 1) sg += rfy[r] * sy;
            if (T > 2) sg += rfz[r] * sz;
            if (T > 3) sg += rfw[r] * sw;
            float e = (m <= rw0 + r) ? __expf(bf2f(cv[r]) * sg) : 0.f;
            S[r] += e;
        }
    }
#pragma unroll
    for (int off = 32; off > 0; off >>= 1) {
#pragma unroll
        for (int r = 0; r < 4; r++) S[r] += __shfl_down(S[r], off);
    }
    if (lane < 4) {
        float v = (lane == 0) ? S[0] : (lane == 1) ? S[1] : (lane == 2) ? S[2] : S[3];
        // lane 0 holds reduced S[r] for all r; redistribute via readlane-free trick: write from lane 0 only
    }
    if (lane == 0) {
#pragma unroll
        for (int r = 0; r < 4; r++) Lrow[colbase + rw0 + r] = fmaxf(S[r], 1e-30f);
    }
}

// ---------------- pass B: received[m] += sum_n attn[n][m]; rows split x2; n-loop unrolled x4
template <int T>
__global__ __launch_bounds__(256) void k_colsum(const ushort_t* __restrict__ compat,
        const float4* __restrict__ charges4, const float* __restrict__ stepp,
        const float* __restrict__ Lrow, float* __restrict__ received) {
    __shared__ float sums[128];
    int bid = blockIdx.x;
    int b = bid / 272, rem = bid % 272;
    int z = rem & 1, r = rem >> 1, ti, tj;
    tri_decode(r, ti, tj);
    int tid = threadIdx.x;
    int ml = tid & 127, half = tid >> 7;
    int m = tj * 128 + ml;
    int mid = b * 2048 + m;
    float step = stepp[0];
    float cx = 0.f, cy = 0.f, cz = 0.f, cw = 0.f;
    if (T > 0) {
        float4 cm = charges4[mid];
        cx = step * cm.x;
        if (T > 1) cy = step * cm.y;
        if (T > 2) cz = step * cm.z;
        if (T > 3) cw = step * cm.w;
    }
    float acc = 0.f;
    bool diag = (ti == tj);
    for (int k = 0; k < 32; k += 4) {
        ushort_t cvv[4];
        float Liv[4];
        float sgv[4];
        int nls[4];
#pragma unroll
        for (int u = 0; u < 4; u++) {
            nls[u] = z * 64 + half + 2 * (k + u);
            int nid = b * 2048 + ti * 128 + nls[u];
            cvv[u] = compat[(long)nid * 2048 + m];
            Liv[u] = Lrow[nid];
            float sg = 1.f;
            if (T > 0) {
                float4 cn = charges4[nid];
                sg += cx * cn.x;
                if (T > 1) sg += cy * cn.y;
                if (T > 2) sg += cz * cn.z;
                if (T > 3) sg += cw * cn.w;
            }
            sgv[u] = sg;
        }
#pragma unroll
        for (int u = 0; u < 4; u++) {
            float p = __expf(bf2f(cvv[u]) * sgv[u]) * (1.0f / Liv[u]);
            if (!diag || m <= ti * 128 + nls[u]) acc += p;
        }
    }
    if (half == 0) sums[ml] = acc;
    __syncthreads();
    if (half == 1) sums[ml] += acc;
    __syncthreads();
    if (tid < 128) atomicAdd(&received[b * 2048 + tj * 128 + tid], sums[tid]);
}

// ---------------- charge update t (writes charges4 component T-1; re-zeroes received)
template <int T>
__global__ void k_charge(float* __restrict__ received, const float* __restrict__ charge0,
                         float4* __restrict__ charges4, const float* __restrict__ decayp) {
    int i = blockIdx.x * 256 + threadIdx.x;
    if (i >= 8192) return;
    float decay = decayp[0];
    float rcv = received[i];
    float sg = 1.0f / (1.0f + __expf(1.0f - rcv));
    float prev = (T == 1) ? charge0[i] : ((const float*)&charges4[i])[T - 2];
    ((float*)&charges4[i])[T - 1] = prev * (1.f - decay * sg);
    received[i] = 0.f;
}

// ---------------- final attention + PV, self-normalizing (512 blocks, col-split waves)
__global__ __launch_bounds__(256) void k_pv(const ushort_t* __restrict__ compat,
        const float4* __restrict__ charges4, const float* __restrict__ stepp,
        const ushort_t* __restrict__ VbT, float* __restrict__ Oacc) {
    __shared__ float accL[3][64][17];
    __shared__ float ssL[4][16];
    int bid = blockIdx.x;
    int b = bid & 3, rtile = 127 - (bid >> 2);  // big tiles dispatched first
    int r0 = rtile * 16;
    int w = threadIdx.x >> 6, lane = threadIdx.x & 63;
    int l16 = lane & 15, quad = lane >> 4;
    int rowl = r0 + l16;
    int rid = b * 2048 + rowl;
    float step = stepp[0];
    float4 c4 = charges4[rid];
    float rx = step * c4.x, ry = step * c4.y, rz = step * c4.z, rw = step * c4.w;
    const ushort_t* crow = compat + (long)rid * 2048;
    f32x4 acc[4] = {};
    float Ss = 0.f;
    int colend = r0 + 16;
    for (int kc = w * 32; kc < colend; kc += 128) {
        int mk = kc + quad * 8;
        u16x8 cv = *reinterpret_cast<const u16x8*>(crow + mk);
        const float4* chp = charges4 + b * 2048 + mk;
        bf16x8 pf;
#pragma unroll
        for (int j = 0; j < 8; j++) {
            float4 ch = chp[j];
            float sg = 1.f + rx * ch.x + ry * ch.y + rz * ch.z + rw * ch.w;
            float p = (mk + j <= rowl) ? __expf(bf2f(cv[j]) * sg) : 0.f;
            Ss += p;
            pf[j] = f2bf(p);
        }
        bf16x8 vf[4];
#pragma unroll
        for (int f = 0; f < 4; f++)
            vf[f] = *reinterpret_cast<const bf16x8*>(VbT + (long)(f * 16 + l16) * 8192 + b * 2048 + mk);
#pragma unroll
        for (int f = 0; f < 4; f++)
            acc[f] = __builtin_amdgcn_mfma_f32_16x16x32_bf16(pf, vf[f], acc[f], 0, 0, 0);
    }
    Ss += __shfl_xor(Ss, 16);
    Ss += __shfl_xor(Ss, 32);
    if (quad == 0) ssL[w][l16] = Ss;
    if (w > 0) {
#pragma unroll
        for (int f = 0; f < 4; f++)
#pragma unroll
            for (int rr = 0; rr < 4; rr++)
                accL[w - 1][lane][f * 4 + rr] = acc[f][rr];
    }
    __syncthreads();
    if (w == 0) {
#pragma unroll
        for (int f = 0; f < 4; f++)
#pragma unroll
            for (int rr = 0; rr < 4; rr++)
                acc[f][rr] += accL[0][lane][f * 4 + rr] + accL[1][lane][f * 4 + rr] + accL[2][lane][f * 4 + rr];
        float Sinv[4];
#pragma unroll
        for (int rr = 0; rr < 4; rr++) {
            int idx = quad * 4 + rr;
            float st = ssL[0][idx] + ssL[1][idx] + ssL[2][idx] + ssL[3][idx];
            Sinv[rr] = 1.f / fmaxf(st, 1e-30f);
        }
#pragma unroll
        for (int f = 0; f < 4; f++)
#pragma unroll
            for (int rr = 0; rr < 4; rr++) {
                int row = r0 + quad * 4 + rr;
                Oacc[(long)(b * 2048 + row) * 64 + f * 16 + l16] = acc[f][rr] * Sinv[rr];
            }
    }
}

// ---------------- out = (Oacc @ Wo^T) * 0.1, fp32 store
__global__ __launch_bounds__(256) void k_oproj(const float* __restrict__ Oacc,
                                               const float* __restrict__ Wo,
                                               float* __restrict__ out) {
    int mt = blockIdx.x & 63, nt = blockIdx.x >> 6;
    int wave = threadIdx.x >> 6, lane = threadIdx.x & 63;
    int wm = wave >> 1, wn = wave & 1;
    int l16 = lane & 15, quad = lane >> 4;
    int row0 = mt * 128 + wm * 64;
    int col0 = nt * 128 + wn * 64;
    f32x4 acc[4][4] = {};
#pragma unroll
    for (int kc = 0; kc < 64; kc += 32) {
        int ko = kc + quad * 8;
        bf16x8 af[4], bfm[4];
#pragma unroll
        for (int f = 0; f < 4; f++) af[f] = ld8f(Oacc + (long)(row0 + f * 16 + l16) * 64 + ko);
#pragma unroll
        for (int f = 0; f < 4; f++) bfm[f] = ld8f(Wo + (long)(col0 + f * 16 + l16) * 64 + ko);
#pragma unroll
        for (int i = 0; i < 4; i++)
#pragma unroll
            for (int j = 0; j < 4; j++)
                acc[i][j] = __builtin_amdgcn_mfma_f32_16x16x32_bf16(af[i], bfm[j], acc[i][j], 0, 0, 0);
    }
#pragma unroll
    for (int i = 0; i < 4; i++)
#pragma unroll
        for (int j = 0; j < 4; j++)
#pragma unroll
            for (int rr = 0; rr < 4; rr++) {
                long rowg = row0 + i * 16 + quad * 4 + rr;
                int colg = col0 + j * 16 + l16;
                out[rowg * 1024 + colg] = acc[i][j][rr] * 0.1f;
            }
}

extern "C" void kernel_launch(void* const* d_in, const int* in_sizes, int n_in,
                              void* d_out, int out_size, void* d_ws, size_t ws_size,
                              hipStream_t stream) {
    const float* hidden = (const float*)d_in[0];
    const float* W1 = (const float*)d_in[1];
    const float* b1 = (const float*)d_in[2];
    const float* W2 = (const float*)d_in[3];
    const float* b2 = (const float*)d_in[4];
    const float* Wq = (const float*)d_in[5];
    const float* Wk = (const float*)d_in[6];
    const float* Wc = (const float*)d_in[7];
    const float* bc = (const float*)d_in[8];
    const float* Wv = (const float*)d_in[9];
    const float* Wo = (const float*)d_in[10];
    const float* stepp = (const float*)d_in[11];
    const float* decayp = (const float*)d_in[12];

    char* ws = (char*)d_ws;
    size_t off = 0;
    auto alloc = [&](size_t bytes) {
        void* p = ws + off;
        off += (bytes + 255) & ~(size_t)255;
        return p;
    };
    ushort_t* compat = (ushort_t*)alloc(8192UL * 2048 * 2);  // 32 MiB bf16
    float* Ff = (float*)alloc(8192UL * 64 * 4);              // 2 MiB
    ushort_t* Qb = (ushort_t*)alloc(8192UL * 64 * 2);
    ushort_t* Kb = (ushort_t*)alloc(8192UL * 64 * 2);
    ushort_t* VbT = (ushort_t*)alloc(64UL * 8192 * 2);
    float* Oacc = (float*)alloc(8192UL * 64 * 4);
    float4* charges4 = (float4*)alloc(8192UL * 16);
    float* charge0 = (float*)alloc(8192UL * 4);
    float* Lrow = (float*)alloc(8192UL * 4);
    float* received = (float*)alloc(8192UL * 4);
    (void)ws_size; (void)in_sizes; (void)n_in; (void)out_size;

    k_fv<<<512, 256, 0, stream>>>(hidden, W1, Wv, Ff, VbT);
    k_feat<<<256, 256, 0, stream>>>(Ff, b1, W2, b2, Wq, Wk, Wc, bc, Qb, Kb, charge0, received);
    k_compat<<<544, 256, 0, stream>>>(Qb, Kb, compat);

    k_rowstats<0><<<512, 256, 0, stream>>>(compat, charges4, stepp, Lrow);
    k_colsum<0><<<1088, 256, 0, stream>>>(compat, charges4, stepp, Lrow, received);
    k_charge<1><<<32, 256, 0, stream>>>(received, charge0, charges4, decayp);

    k_rowstats<1><<<512, 256, 0, stream>>>(compat, charges4, stepp, Lrow);
    k_colsum<1><<<1088, 256, 0, stream>>>(compat, charges4, stepp, Lrow, received);
    k_charge<2><<<32, 256, 0, stream>>>(received, charge0, charges4, decayp);

    k_rowstats<2><<<512, 256, 0, stream>>>(compat, charges4, stepp, Lrow);
    k_colsum<2><<<1088, 256, 0, stream>>>(compat, charges4, stepp, Lrow, received);
    k_charge<3><<<32, 256, 0, stream>>>(received, charge0, charges4, decayp);

    k_rowstats<3><<<512, 256, 0, stream>>>(compat, charges4, stepp, Lrow);
    k_colsum<3><<<1088, 256, 0, stream>>>(compat, charges4, stepp, Lrow, received);
    k_charge<4><<<32, 256, 0, stream>>>(received, charge0, charges4, decayp);

    k_pv<<<512, 256, 0, stream>>>(compat, charges4, stepp, VbT, Oacc);
    k_oproj<<<512, 256, 0, stream>>>(Oacc, Wo, (float*)d_out);
}

// Round 8
// 303.504 us; speedup vs baseline: 1.1594x; 1.0905x over previous
//
#include <hip/hip_runtime.h>
#include <hip/hip_bf16.h>

typedef unsigned short ushort_t;
typedef short bf16x8 __attribute__((ext_vector_type(8)));
typedef ushort_t u16x8 __attribute__((ext_vector_type(8)));
typedef float f32x4 __attribute__((ext_vector_type(4)));

#define DEV static __device__ __forceinline__

DEV float bf2f(ushort_t u) { unsigned v = ((unsigned)u) << 16; float f; __builtin_memcpy(&f, &v, 4); return f; }
DEV short f2bf(float x) { __hip_bfloat16 h = __float2bfloat16(x); short s; __builtin_memcpy(&s, &h, 2); return s; }
DEV float sigm(float x) { return 1.0f / (1.0f + __expf(-x)); }

DEV bf16x8 cvt8(float4 a0, float4 a1) {
    bf16x8 t;
    t[0] = f2bf(a0.x); t[1] = f2bf(a0.y); t[2] = f2bf(a0.z); t[3] = f2bf(a0.w);
    t[4] = f2bf(a1.x); t[5] = f2bf(a1.y); t[6] = f2bf(a1.z); t[7] = f2bf(a1.w);
    return t;
}
DEV bf16x8 ld8f(const float* __restrict__ p) {
    return cvt8(*reinterpret_cast<const float4*>(p), *reinterpret_cast<const float4*>(p + 4));
}

// ---------------- K1: FVp[kh][8192][128] partial = hidden[:, kh-half] @ [W1;Wv]^T
// K-split x2 (1024 blocks -> 12-16 waves/CU) + launch_bounds(256,3) so the 24-load
// batch actually gets VGPRs (R7: default bounds clamped to 64 VGPR and serialized).
__global__ __launch_bounds__(256, 3) void k_fv(const float* __restrict__ h,
        const float* __restrict__ W1, const float* __restrict__ Wv,
        float* __restrict__ FVp) {
    int bid = blockIdx.x;
    int kh = bid & 1;
    int m0 = (bid >> 1) * 16;
    int wave = threadIdx.x >> 6, lane = threadIdx.x & 63;
    int l16 = lane & 15, quad = lane >> 4;
    const float* B = (wave < 2) ? W1 : Wv;
    int cb = (wave & 1) * 32;
    f32x4 acc[2] = {};
    const float* arow = h + (long)(m0 + l16) * 1024 + kh * 512;
    const float* brow0 = B + (long)(cb + l16) * 1024 + kh * 512;
    const float* brow1 = B + (long)(cb + 16 + l16) * 1024 + kh * 512;
    for (int kc = 0; kc < 512; kc += 128) {
        float4 ra[4][2], r0[4][2], r1[4][2];
#pragma unroll
        for (int u = 0; u < 4; u++) {
            int ko = kc + u * 32 + quad * 8;
            ra[u][0] = *reinterpret_cast<const float4*>(arow + ko);
            ra[u][1] = *reinterpret_cast<const float4*>(arow + ko + 4);
            r0[u][0] = *reinterpret_cast<const float4*>(brow0 + ko);
            r0[u][1] = *reinterpret_cast<const float4*>(brow0 + ko + 4);
            r1[u][0] = *reinterpret_cast<const float4*>(brow1 + ko);
            r1[u][1] = *reinterpret_cast<const float4*>(brow1 + ko + 4);
        }
#pragma unroll
        for (int u = 0; u < 4; u++) {
            bf16x8 af = cvt8(ra[u][0], ra[u][1]);
            bf16x8 b0 = cvt8(r0[u][0], r0[u][1]);
            bf16x8 b1v = cvt8(r1[u][0], r1[u][1]);
            acc[0] = __builtin_amdgcn_mfma_f32_16x16x32_bf16(af, b0, acc[0], 0, 0, 0);
            acc[1] = __builtin_amdgcn_mfma_f32_16x16x32_bf16(af, b1v, acc[1], 0, 0, 0);
        }
    }
    int colbase = ((wave >= 2) ? 64 : 0) + cb;
    float* outp = FVp + (long)kh * 8192 * 128;
#pragma unroll
    for (int c = 0; c < 2; c++)
#pragma unroll
        for (int rr = 0; rr < 4; rr++) {
            int row = m0 + quad * 4 + rr;
            outp[(long)row * 128 + colbase + c * 16 + l16] = acc[c][rr];
        }
}

// ---------------- K1b: VbT[64][8192] = transpose(sum of FVp halves, cols 64..127) as bf16
__global__ __launch_bounds__(256) void k_vbt(const float* __restrict__ FVp, ushort_t* __restrict__ VbT) {
    __shared__ float tL[64][65];
    int r0 = blockIdx.x * 64;
    for (int i = threadIdx.x; i < 64 * 64; i += 256) {
        int r = i >> 6, d = i & 63;
        long idx = (long)(r0 + r) * 128 + 64 + d;
        tL[r][d] = FVp[idx] + FVp[8192L * 128 + idx];
    }
    __syncthreads();
    for (int i = threadIdx.x; i < 64 * 64; i += 256) {
        int d = i >> 6, r = i & 63;
        VbT[(long)d * 8192 + r0 + r] = (ushort_t)f2bf(tL[r][d]);
    }
}

// ---------------- K2: gelu -> features -> Q,K,charge0; zero received. 256 blocks x 32 rows.
__global__ __launch_bounds__(256) void k_feat(const float* __restrict__ FVp,
        const float* __restrict__ b1, const float* __restrict__ W2, const float* __restrict__ b2,
        const float* __restrict__ Wq, const float* __restrict__ Wk,
        const float* __restrict__ Wc, const float* __restrict__ bc,
        ushort_t* __restrict__ Qb, ushort_t* __restrict__ Kb,
        float* __restrict__ charge0, float* __restrict__ received) {
    __shared__ float w2L[28 * 65], wqL[64 * 29], wkL[64 * 29], wcL[28], b2L[28];
    __shared__ float fL[4][64], featL[4][28];
    int tid = threadIdx.x;
    for (int i = tid; i < 28 * 64; i += 256) w2L[(i >> 6) * 65 + (i & 63)] = W2[i];
    for (int i = tid; i < 64 * 28; i += 256) {
        int r = i / 28, c = i - r * 28;
        wqL[r * 29 + c] = Wq[i];
        wkL[r * 29 + c] = Wk[i];
    }
    if (tid < 28) { wcL[tid] = Wc[tid]; b2L[tid] = b2[tid]; }
    __syncthreads();
    int w = tid >> 6, lane = tid & 63;
    float b1v = b1[lane];
    float bcv = bc[0];
    for (int it = 0; it < 8; it++) {
        int row = blockIdx.x * 32 + it * 4 + w;
        long idx = (long)row * 128 + lane;
        float x = FVp[idx] + FVp[8192L * 128 + idx] + b1v;
        fL[w][lane] = 0.5f * x * (1.0f + erff(x * 0.70710678118654752f));
        __syncthreads();
        if (lane < 28) {
            float s = b2L[lane];
#pragma unroll
            for (int j = 0; j < 64; j++) s += fL[w][j] * w2L[lane * 65 + j];
            featL[w][lane] = sigm(s);
        }
        __syncthreads();
        float q = 0.f, k = 0.f;
#pragma unroll
        for (int i = 0; i < 28; i++) {
            float fv = featL[w][i];
            q += fv * wqL[lane * 29 + i];
            k += fv * wkL[lane * 29 + i];
        }
        Qb[row * 64 + lane] = (ushort_t)f2bf(q * 0.125f);  // fold 1/sqrt(64)
        Kb[row * 64 + lane] = (ushort_t)f2bf(k);
        if (lane == 0) {
            float c = bcv;
#pragma unroll
            for (int i = 0; i < 28; i++) c += featL[w][i] * wcL[i];
            charge0[row] = sigm(c);
            received[row] = 0.f;
        }
        __syncthreads();
    }
}

DEV void tri_decode(int r, int& ti, int& tj) {
    int t = (int)((sqrtf(8.f * (float)r + 1.f) - 1.f) * 0.5f);
    while ((t + 1) * (t + 2) / 2 <= r) t++;
    while (t * (t + 1) / 2 > r) t--;
    ti = t;
    tj = r - t * (t + 1) / 2;
}

// ---------------- K3: compat[(b*2048+n)][m] = (Q/8)·K, causal 128x128 tiles, bf16 store
__global__ __launch_bounds__(256) void k_compat(const ushort_t* __restrict__ Qb,
                                                const ushort_t* __restrict__ Kb,
                                                ushort_t* __restrict__ compat) {
    int bid = blockIdx.x;
    int b = bid / 136, r = bid % 136, ti, tj;
    tri_decode(r, ti, tj);
    int wave = threadIdx.x >> 6, lane = threadIdx.x & 63;
    int l16 = lane & 15, quad = lane >> 4;
    int rbase = b * 2048 + ti * 128 + wave * 32;
    int cbase = b * 2048 + tj * 128;
    f32x4 acc[2][8] = {};
#pragma unroll
    for (int kc = 0; kc < 64; kc += 32) {
        int ko = kc + quad * 8;
        bf16x8 af[2], bf[8];
#pragma unroll
        for (int f = 0; f < 2; f++) af[f] = *reinterpret_cast<const bf16x8*>(Qb + (long)(rbase + f * 16 + l16) * 64 + ko);
#pragma unroll
        for (int f = 0; f < 8; f++) bf[f] = *reinterpret_cast<const bf16x8*>(Kb + (long)(cbase + f * 16 + l16) * 64 + ko);
#pragma unroll
        for (int i = 0; i < 2; i++)
#pragma unroll
            for (int j = 0; j < 8; j++)
                acc[i][j] = __builtin_amdgcn_mfma_f32_16x16x32_bf16(af[i], bf[j], acc[i][j], 0, 0, 0);
    }
    int colt = tj * 128;
#pragma unroll
    for (int i = 0; i < 2; i++)
#pragma unroll
        for (int j = 0; j < 8; j++)
#pragma unroll
            for (int rr = 0; rr < 4; rr++) {
                long rowg = rbase + i * 16 + quad * 4 + rr;
                int col = colt + j * 16 + l16;
                compat[rowg * 2048 + col] = (ushort_t)f2bf(acc[i][j][rr]);
            }
}

// ---------------- pass A: Lp[z][n] = partial sum over column-half z of exp(compat*sigma).
// 1024 blocks = 128 row-tiles x 4 batch x 2 col-halves; wave = 4 rows sharing column charges.
template <int T>
__global__ __launch_bounds__(256) void k_rowstats(const ushort_t* __restrict__ compat,
        const float4* __restrict__ charges4, const float* __restrict__ stepp,
        float* __restrict__ Lp) {
    int bid = blockIdx.x;
    int z = bid & 1;
    int b = (bid >> 1) & 3;
    int rt = 127 - (bid >> 3);   // big tiles first
    int w = threadIdx.x >> 6, lane = threadIdx.x & 63;
    int rw0 = rt * 16 + w * 4;
    int colbase = b * 2048;
    float step = stepp[0];
    float rfx[4] = {}, rfy[4] = {}, rfz[4] = {}, rfw[4] = {};
    if (T > 0) {
#pragma unroll
        for (int r = 0; r < 4; r++) {
            float4 c4 = charges4[colbase + rw0 + r];
            rfx[r] = step * c4.x;
            if (T > 1) rfy[r] = step * c4.y;
            if (T > 2) rfz[r] = step * c4.z;
            if (T > 3) rfw[r] = step * c4.w;
        }
    }
    const ushort_t* crow0 = compat + (long)(colbase + rw0) * 2048;
    float S[4] = {0.f, 0.f, 0.f, 0.f};
    int nmax = rw0 + 3;
    int mhi = min(nmax, z * 1024 + 1023);
    for (int m = z * 1024 + lane; m <= mhi; m += 64) {
        ushort_t cv[4];
#pragma unroll
        for (int r = 0; r < 4; r++) cv[r] = crow0[(long)r * 2048 + m];
        float sx = 0.f, sy = 0.f, sz = 0.f, sw = 0.f;
        if (T > 0) {
            float4 ch = charges4[colbase + m];
            sx = ch.x; sy = ch.y; sz = ch.z; sw = ch.w;
        }
#pragma unroll
        for (int r = 0; r < 4; r++) {
            float sg = 1.f;
            if (T > 0) sg += rfx[r] * sx;
            if (T > 1) sg += rfy[r] * sy;
            if (T > 2) sg += rfz[r] * sz;
            if (T > 3) sg += rfw[r] * sw;
            float e = (m <= rw0 + r) ? __expf(bf2f(cv[r]) * sg) : 0.f;
            S[r] += e;
        }
    }
#pragma unroll
    for (int off = 32; off > 0; off >>= 1) {
#pragma unroll
        for (int r = 0; r < 4; r++) S[r] += __shfl_down(S[r], off);
    }
    if (lane == 0) {
#pragma unroll
        for (int r = 0; r < 4; r++) Lp[z * 8192 + colbase + rw0 + r] = S[r];
    }
}

// ---------------- pass B: received[m] += sum_n attn[n][m]; n-split x4; n-side data in LDS.
template <int T>
__global__ __launch_bounds__(256) void k_colsum(const ushort_t* __restrict__ compat,
        const float4* __restrict__ charges4, const float* __restrict__ stepp,
        const float* __restrict__ Lp, float* __restrict__ received) {
    __shared__ float sums[128];
    __shared__ float nvx[32], nvy[32], nvz[32], nvw[32], nLi[32];
    int bid = blockIdx.x;
    int b = bid / 544, rem = bid % 544;
    int q = rem & 3, r = rem >> 2, ti, tj;
    tri_decode(r, ti, tj);
    int tid = threadIdx.x;
    int ml = tid & 127, half = tid >> 7;
    if (tid < 32) {
        int nid = b * 2048 + ti * 128 + q * 32 + tid;
        nLi[tid] = 1.0f / fmaxf(Lp[nid] + Lp[8192 + nid], 1e-30f);
        if (T > 0) {
            float4 cn = charges4[nid];
            nvx[tid] = cn.x;
            if (T > 1) nvy[tid] = cn.y;
            if (T > 2) nvz[tid] = cn.z;
            if (T > 3) nvw[tid] = cn.w;
        }
    }
    __syncthreads();
    int m = tj * 128 + ml;
    int mid = b * 2048 + m;
    float step = stepp[0];
    float cx = 0.f, cy = 0.f, cz = 0.f, cw = 0.f;
    if (T > 0) {
        float4 cm = charges4[mid];
        cx = step * cm.x;
        if (T > 1) cy = step * cm.y;
        if (T > 2) cz = step * cm.z;
        if (T > 3) cw = step * cm.w;
    }
    float acc = 0.f;
    bool diag = (ti == tj);
    const ushort_t* cbase_p = compat + (long)(b * 2048 + ti * 128 + q * 32) * 2048 + m;
    for (int k = 0; k < 16; k += 4) {
        ushort_t cvv[4];
        int nli[4];
#pragma unroll
        for (int u = 0; u < 4; u++) {
            nli[u] = half + 2 * (k + u);
            cvv[u] = cbase_p[(long)nli[u] * 2048];
        }
#pragma unroll
        for (int u = 0; u < 4; u++) {
            float sg = 1.f;
            if (T > 0) sg += cx * nvx[nli[u]];
            if (T > 1) sg += cy * nvy[nli[u]];
            if (T > 2) sg += cz * nvz[nli[u]];
            if (T > 3) sg += cw * nvw[nli[u]];
            float p = __expf(bf2f(cvv[u]) * sg) * nLi[nli[u]];
            if (!diag || m <= ti * 128 + q * 32 + nli[u]) acc += p;
        }
    }
    if (half == 0) sums[ml] = acc;
    __syncthreads();
    if (half == 1) sums[ml] += acc;
    __syncthreads();
    if (tid < 128) atomicAdd(&received[b * 2048 + tj * 128 + tid], sums[tid]);
}

// ---------------- charge update t (writes charges4 component T-1; re-zeroes received)
template <int T>
__global__ void k_charge(float* __restrict__ received, const float* __restrict__ charge0,
                         float4* __restrict__ charges4, const float* __restrict__ decayp) {
    int i = blockIdx.x * 256 + threadIdx.x;
    if (i >= 8192) return;
    float decay = decayp[0];
    float rcv = received[i];
    float sg = 1.0f / (1.0f + __expf(1.0f - rcv));
    float prev = (T == 1) ? charge0[i] : ((const float*)&charges4[i])[T - 2];
    ((float*)&charges4[i])[T - 1] = prev * (1.f - decay * sg);
    received[i] = 0.f;
}

// ---------------- final attention + PV, self-normalizing (512 blocks, col-split waves)
__global__ __launch_bounds__(256) void k_pv(const ushort_t* __restrict__ compat,
        const float4* __restrict__ charges4, const float* __restrict__ stepp,
        const ushort_t* __restrict__ VbT, float* __restrict__ Oacc) {
    __shared__ float accL[3][64][17];
    __shared__ float ssL[4][16];
    int bid = blockIdx.x;
    int b = bid & 3, rtile = 127 - (bid >> 2);  // big tiles dispatched first
    int r0 = rtile * 16;
    int w = threadIdx.x >> 6, lane = threadIdx.x & 63;
    int l16 = lane & 15, quad = lane >> 4;
    int rowl = r0 + l16;
    int rid = b * 2048 + rowl;
    float step = stepp[0];
    float4 c4 = charges4[rid];
    float rx = step * c4.x, ry = step * c4.y, rz = step * c4.z, rw = step * c4.w;
    const ushort_t* crow = compat + (long)rid * 2048;
    f32x4 acc[4] = {};
    float Ss = 0.f;
    int colend = r0 + 16;
    for (int kc = w * 32; kc < colend; kc += 128) {
        int mk = kc + quad * 8;
        u16x8 cv = *reinterpret_cast<const u16x8*>(crow + mk);
        const float4* chp = charges4 + b * 2048 + mk;
        bf16x8 pf;
#pragma unroll
        for (int j = 0; j < 8; j++) {
            float4 ch = chp[j];
            float sg = 1.f + rx * ch.x + ry * ch.y + rz * ch.z + rw * ch.w;
            float p = (mk + j <= rowl) ? __expf(bf2f(cv[j]) * sg) : 0.f;
            Ss += p;
            pf[j] = f2bf(p);
        }
        bf16x8 vf[4];
#pragma unroll
        for (int f = 0; f < 4; f++)
            vf[f] = *reinterpret_cast<const bf16x8*>(VbT + (long)(f * 16 + l16) * 8192 + b * 2048 + mk);
#pragma unroll
        for (int f = 0; f < 4; f++)
            acc[f] = __builtin_amdgcn_mfma_f32_16x16x32_bf16(pf, vf[f], acc[f], 0, 0, 0);
    }
    Ss += __shfl_xor(Ss, 16);
    Ss += __shfl_xor(Ss, 32);
    if (quad == 0) ssL[w][l16] = Ss;
    if (w > 0) {
#pragma unroll
        for (int f = 0; f < 4; f++)
#pragma unroll
            for (int rr = 0; rr < 4; rr++)
                accL[w - 1][lane][f * 4 + rr] = acc[f][rr];
    }
    __syncthreads();
    if (w == 0) {
#pragma unroll
        for (int f = 0; f < 4; f++)
#pragma unroll
            for (int rr = 0; rr < 4; rr++)
                acc[f][rr] += accL[0][lane][f * 4 + rr] + accL[1][lane][f * 4 + rr] + accL[2][lane][f * 4 + rr];
        float Sinv[4];
#pragma unroll
        for (int rr = 0; rr < 4; rr++) {
            int idx = quad * 4 + rr;
            float st = ssL[0][idx] + ssL[1][idx] + ssL[2][idx] + ssL[3][idx];
            Sinv[rr] = 1.f / fmaxf(st, 1e-30f);
        }
#pragma unroll
        for (int f = 0; f < 4; f++)
#pragma unroll
            for (int rr = 0; rr < 4; rr++) {
                int row = r0 + quad * 4 + rr;
                Oacc[(long)(b * 2048 + row) * 64 + f * 16 + l16] = acc[f][rr] * Sinv[rr];
            }
    }
}

// ---------------- out = (Oacc @ Wo^T) * 0.1, fp32 store
__global__ __launch_bounds__(256) void k_oproj(const float* __restrict__ Oacc,
                                               const float* __restrict__ Wo,
                                               float* __restrict__ out) {
    int mt = blockIdx.x & 63, nt = blockIdx.x >> 6;
    int wave = threadIdx.x >> 6, lane = threadIdx.x & 63;
    int wm = wave >> 1, wn = wave & 1;
    int l16 = lane & 15, quad = lane >> 4;
    int row0 = mt * 128 + wm * 64;
    int col0 = nt * 128 + wn * 64;
    f32x4 acc[4][4] = {};
#pragma unroll
    for (int kc = 0; kc < 64; kc += 32) {
        int ko = kc + quad * 8;
        bf16x8 af[4], bfm[4];
#pragma unroll
        for (int f = 0; f < 4; f++) af[f] = ld8f(Oacc + (long)(row0 + f * 16 + l16) * 64 + ko);
#pragma unroll
        for (int f = 0; f < 4; f++) bfm[f] = ld8f(Wo + (long)(col0 + f * 16 + l16) * 64 + ko);
#pragma unroll
        for (int i = 0; i < 4; i++)
#pragma unroll
            for (int j = 0; j < 4; j++)
                acc[i][j] = __builtin_amdgcn_mfma_f32_16x16x32_bf16(af[i], bfm[j], acc[i][j], 0, 0, 0);
    }
#pragma unroll
    for (int i = 0; i < 4; i++)
#pragma unroll
        for (int j = 0; j < 4; j++)
#pragma unroll
            for (int rr = 0; rr < 4; rr++) {
                long rowg = row0 + i * 16 + quad * 4 + rr;
                int colg = col0 + j * 16 + l16;
                out[rowg * 1024 + colg] = acc[i][j][rr] * 0.1f;
            }
}

extern "C" void kernel_launch(void* const* d_in, const int* in_sizes, int n_in,
                              void* d_out, int out_size, void* d_ws, size_t ws_size,
                              hipStream_t stream) {
    const float* hidden = (const float*)d_in[0];
    const float* W1 = (const float*)d_in[1];
    const float* b1 = (const float*)d_in[2];
    const float* W2 = (const float*)d_in[3];
    const float* b2 = (const float*)d_in[4];
    const float* Wq = (const float*)d_in[5];
    const float* Wk = (const float*)d_in[6];
    const float* Wc = (const float*)d_in[7];
    const float* bc = (const float*)d_in[8];
    const float* Wv = (const float*)d_in[9];
    const float* Wo = (const float*)d_in[10];
    const float* stepp = (const float*)d_in[11];
    const float* decayp = (const float*)d_in[12];

    char* ws = (char*)d_ws;
    size_t off = 0;
    auto alloc = [&](size_t bytes) {
        void* p = ws + off;
        off += (bytes + 255) & ~(size_t)255;
        return p;
    };
    ushort_t* compat = (ushort_t*)alloc(8192UL * 2048 * 2);  // 32 MiB bf16
    float* FVp = (float*)alloc(2UL * 8192 * 128 * 4);        // 8 MiB (2 K-half partials)
    ushort_t* Qb = (ushort_t*)alloc(8192UL * 64 * 2);
    ushort_t* Kb = (ushort_t*)alloc(8192UL * 64 * 2);
    ushort_t* VbT = (ushort_t*)alloc(64UL * 8192 * 2);
    float* Oacc = (float*)alloc(8192UL * 64 * 4);
    float4* charges4 = (float4*)alloc(8192UL * 16);
    float* charge0 = (float*)alloc(8192UL * 4);
    float* Lp = (float*)alloc(2UL * 8192 * 4);               // 2 column-half partials
    float* received = (float*)alloc(8192UL * 4);
    (void)ws_size; (void)in_sizes; (void)n_in; (void)out_size;

    k_fv<<<1024, 256, 0, stream>>>(hidden, W1, Wv, FVp);
    k_vbt<<<128, 256, 0, stream>>>(FVp, VbT);
    k_feat<<<256, 256, 0, stream>>>(FVp, b1, W2, b2, Wq, Wk, Wc, bc, Qb, Kb, charge0, received);
    k_compat<<<544, 256, 0, stream>>>(Qb, Kb, compat);

    k_rowstats<0><<<1024, 256, 0, stream>>>(compat, charges4, stepp, Lp);
    k_colsum<0><<<2176, 256, 0, stream>>>(compat, charges4, stepp, Lp, received);
    k_charge<1><<<32, 256, 0, stream>>>(received, charge0, charges4, decayp);

    k_rowstats<1><<<1024, 256, 0, stream>>>(compat, charges4, stepp, Lp);
    k_colsum<1><<<2176, 256, 0, stream>>>(compat, charges4, stepp, Lp, received);
    k_charge<2><<<32, 256, 0, stream>>>(received, charge0, charges4, decayp);

    k_rowstats<2><<<1024, 256, 0, stream>>>(compat, charges4, stepp, Lp);
    k_colsum<2><<<2176, 256, 0, stream>>>(compat, charges4, stepp, Lp, received);
    k_charge<3><<<32, 256, 0, stream>>>(received, charge0, charges4, decayp);

    k_rowstats<3><<<1024, 256, 0, stream>>>(compat, charges4, stepp, Lp);
    k_colsum<3><<<2176, 256, 0, stream>>>(compat, charges4, stepp, Lp, received);
    k_charge<4><<<32, 256, 0, stream>>>(received, charge0, charges4, decayp);

    k_pv<<<512, 256, 0, stream>>>(compat, charges4, stepp, VbT, Oacc);
    k_oproj<<<512, 256, 0, stream>>>(Oacc, Wo, (float*)d_out);
}

// Round 9
// 291.939 us; speedup vs baseline: 1.2053x; 1.0396x over previous
//
#include <hip/hip_runtime.h>
#include <hip/hip_bf16.h>

typedef unsigned short ushort_t;
typedef short bf16x8 __attribute__((ext_vector_type(8)));
typedef ushort_t u16x8 __attribute__((ext_vector_type(8)));
typedef float f32x4 __attribute__((ext_vector_type(4)));

#define DEV static __device__ __forceinline__

DEV float bf2f(ushort_t u) { unsigned v = ((unsigned)u) << 16; float f; __builtin_memcpy(&f, &v, 4); return f; }
DEV short f2bf(float x) { __hip_bfloat16 h = __float2bfloat16(x); short s; __builtin_memcpy(&s, &h, 2); return s; }
DEV float sigm(float x) { return 1.0f / (1.0f + __expf(-x)); }

DEV bf16x8 cvt8(float4 a0, float4 a1) {
    bf16x8 t;
    t[0] = f2bf(a0.x); t[1] = f2bf(a0.y); t[2] = f2bf(a0.z); t[3] = f2bf(a0.w);
    t[4] = f2bf(a1.x); t[5] = f2bf(a1.y); t[6] = f2bf(a1.z); t[7] = f2bf(a1.w);
    return t;
}
DEV bf16x8 ld8f(const float* __restrict__ p) {
    return cvt8(*reinterpret_cast<const float4*>(p), *reinterpret_cast<const float4*>(p + 4));
}

// ---------------- K0: streaming fp32 -> bf16 convert (8 elems/thread)
__global__ void k_cvt(const float* __restrict__ src, ushort_t* __restrict__ dst, int n8) {
    int i = blockIdx.x * 256 + threadIdx.x;
    if (i >= n8) return;
    const float4* p = reinterpret_cast<const float4*>(src) + (long)i * 2;
    *reinterpret_cast<bf16x8*>(dst + (long)i * 8) = cvt8(p[0], p[1]);
}

// ---------------- K1: Ff[8192][64] = Hb@W1^T (fp32), VbT[64][8192] = (Hb@Wv^T)^T bf16
// bf16 inputs: 3 loads per k-step (was 6 in fp32); batch 4 k-steps (12 loads, 48 VGPR).
__global__ __launch_bounds__(256) void k_fv(const ushort_t* __restrict__ Hb,
        const ushort_t* __restrict__ Wcat,
        float* __restrict__ Ff, ushort_t* __restrict__ VbT) {
    int m0 = blockIdx.x * 16;
    int wave = threadIdx.x >> 6, lane = threadIdx.x & 63;
    int l16 = lane & 15, quad = lane >> 4;
    int cb = (wave & 1) * 32;
    int brow_off = (wave < 2) ? 0 : 64;   // rows 0-63 = W1, 64-127 = Wv
    f32x4 acc[2] = {};
    const ushort_t* arow = Hb + (long)(m0 + l16) * 1024;
    const ushort_t* brow0 = Wcat + (long)(brow_off + cb + l16) * 1024;
    const ushort_t* brow1 = Wcat + (long)(brow_off + cb + 16 + l16) * 1024;
    for (int kc = 0; kc < 1024; kc += 128) {
        bf16x8 a4[4], b04[4], b14[4];
#pragma unroll
        for (int u = 0; u < 4; u++) {
            int ko = kc + u * 32 + quad * 8;
            a4[u] = *reinterpret_cast<const bf16x8*>(arow + ko);
            b04[u] = *reinterpret_cast<const bf16x8*>(brow0 + ko);
            b14[u] = *reinterpret_cast<const bf16x8*>(brow1 + ko);
        }
#pragma unroll
        for (int u = 0; u < 4; u++) {
            acc[0] = __builtin_amdgcn_mfma_f32_16x16x32_bf16(a4[u], b04[u], acc[0], 0, 0, 0);
            acc[1] = __builtin_amdgcn_mfma_f32_16x16x32_bf16(a4[u], b14[u], acc[1], 0, 0, 0);
        }
    }
    bool isV = (wave >= 2);
#pragma unroll
    for (int c = 0; c < 2; c++)
#pragma unroll
        for (int rr = 0; rr < 4; rr++) {
            int row = m0 + quad * 4 + rr;
            int col = cb + c * 16 + l16;
            float v = acc[c][rr];
            if (!isV) Ff[row * 64 + col] = v;
            else VbT[(long)col * 8192 + row] = (ushort_t)f2bf(v);
        }
}

// ---------------- K2: gelu -> features -> Q,K,charge0; zero received. 256 blocks x 32 rows.
__global__ __launch_bounds__(256) void k_feat(const float* __restrict__ Ff,
        const float* __restrict__ b1, const float* __restrict__ W2, const float* __restrict__ b2,
        const float* __restrict__ Wq, const float* __restrict__ Wk,
        const float* __restrict__ Wc, const float* __restrict__ bc,
        ushort_t* __restrict__ Qb, ushort_t* __restrict__ Kb,
        float* __restrict__ charge0, float* __restrict__ received) {
    __shared__ float w2L[28 * 65], wqL[64 * 29], wkL[64 * 29], wcL[28], b2L[28];
    __shared__ float fL[4][64], featL[4][28];
    int tid = threadIdx.x;
    for (int i = tid; i < 28 * 64; i += 256) w2L[(i >> 6) * 65 + (i & 63)] = W2[i];
    for (int i = tid; i < 64 * 28; i += 256) {
        int r = i / 28, c = i - r * 28;
        wqL[r * 29 + c] = Wq[i];
        wkL[r * 29 + c] = Wk[i];
    }
    if (tid < 28) { wcL[tid] = Wc[tid]; b2L[tid] = b2[tid]; }
    __syncthreads();
    int w = tid >> 6, lane = tid & 63;
    float b1v = b1[lane];
    float bcv = bc[0];
    for (int it = 0; it < 8; it++) {
        int row = blockIdx.x * 32 + it * 4 + w;
        float x = Ff[row * 64 + lane] + b1v;
        fL[w][lane] = 0.5f * x * (1.0f + erff(x * 0.70710678118654752f));
        __syncthreads();
        if (lane < 28) {
            float s = b2L[lane];
#pragma unroll
            for (int j = 0; j < 64; j++) s += fL[w][j] * w2L[lane * 65 + j];
            featL[w][lane] = sigm(s);
        }
        __syncthreads();
        float q = 0.f, k = 0.f;
#pragma unroll
        for (int i = 0; i < 28; i++) {
            float fv = featL[w][i];
            q += fv * wqL[lane * 29 + i];
            k += fv * wkL[lane * 29 + i];
        }
        Qb[row * 64 + lane] = (ushort_t)f2bf(q * 0.125f);  // fold 1/sqrt(64)
        Kb[row * 64 + lane] = (ushort_t)f2bf(k);
        if (lane == 0) {
            float c = bcv;
#pragma unroll
            for (int i = 0; i < 28; i++) c += featL[w][i] * wcL[i];
            charge0[row] = sigm(c);
            received[row] = 0.f;
        }
        __syncthreads();
    }
}

DEV void tri_decode(int r, int& ti, int& tj) {
    int t = (int)((sqrtf(8.f * (float)r + 1.f) - 1.f) * 0.5f);
    while ((t + 1) * (t + 2) / 2 <= r) t++;
    while (t * (t + 1) / 2 > r) t--;
    ti = t;
    tj = r - t * (t + 1) / 2;
}

// ---------------- K3: compat[(b*2048+n)][m] = (Q/8)·K, causal 128x128 tiles, bf16 store
__global__ __launch_bounds__(256) void k_compat(const ushort_t* __restrict__ Qb,
                                                const ushort_t* __restrict__ Kb,
                                                ushort_t* __restrict__ compat) {
    int bid = blockIdx.x;
    int b = bid / 136, r = bid % 136, ti, tj;
    tri_decode(r, ti, tj);
    int wave = threadIdx.x >> 6, lane = threadIdx.x & 63;
    int l16 = lane & 15, quad = lane >> 4;
    int rbase = b * 2048 + ti * 128 + wave * 32;
    int cbase = b * 2048 + tj * 128;
    f32x4 acc[2][8] = {};
#pragma unroll
    for (int kc = 0; kc < 64; kc += 32) {
        int ko = kc + quad * 8;
        bf16x8 af[2], bf[8];
#pragma unroll
        for (int f = 0; f < 2; f++) af[f] = *reinterpret_cast<const bf16x8*>(Qb + (long)(rbase + f * 16 + l16) * 64 + ko);
#pragma unroll
        for (int f = 0; f < 8; f++) bf[f] = *reinterpret_cast<const bf16x8*>(Kb + (long)(cbase + f * 16 + l16) * 64 + ko);
#pragma unroll
        for (int i = 0; i < 2; i++)
#pragma unroll
            for (int j = 0; j < 8; j++)
                acc[i][j] = __builtin_amdgcn_mfma_f32_16x16x32_bf16(af[i], bf[j], acc[i][j], 0, 0, 0);
    }
    int colt = tj * 128;
#pragma unroll
    for (int i = 0; i < 2; i++)
#pragma unroll
        for (int j = 0; j < 8; j++)
#pragma unroll
            for (int rr = 0; rr < 4; rr++) {
                long rowg = rbase + i * 16 + quad * 4 + rr;
                int col = colt + j * 16 + l16;
                compat[rowg * 2048 + col] = (ushort_t)f2bf(acc[i][j][rr]);
            }
}

// ---------------- pass A: Lp[z][n] = partial sum over column-half z of exp(compat*sigma).
// Wave = 4 rows; each lane owns an 8-column chunk -> u16x8 compat loads (16 B/lane/row).
template <int T>
__global__ __launch_bounds__(256) void k_rowstats(const ushort_t* __restrict__ compat,
        const float4* __restrict__ charges4, const float* __restrict__ stepp,
        float* __restrict__ Lp) {
    int bid = blockIdx.x;
    int z = bid & 1;
    int b = (bid >> 1) & 3;
    int rt = 127 - (bid >> 3);   // big tiles first
    int w = threadIdx.x >> 6, lane = threadIdx.x & 63;
    int rw0 = rt * 16 + w * 4;
    int colbase = b * 2048;
    if (z == 1 && rt < 64) {     // column-half 1 has no causal work for rows < 1024
        if (lane == 0) {
#pragma unroll
            for (int r = 0; r < 4; r++) Lp[8192 + colbase + rw0 + r] = 0.f;
        }
        return;
    }
    float step = stepp[0];
    float rfx[4] = {}, rfy[4] = {}, rfz[4] = {}, rfw[4] = {};
    if (T > 0) {
#pragma unroll
        for (int r = 0; r < 4; r++) {
            float4 c4 = charges4[colbase + rw0 + r];
            rfx[r] = step * c4.x;
            if (T > 1) rfy[r] = step * c4.y;
            if (T > 2) rfz[r] = step * c4.z;
            if (T > 3) rfw[r] = step * c4.w;
        }
    }
    const ushort_t* crow0 = compat + (long)(colbase + rw0) * 2048;
    int nmax = rw0 + 3;
    float S[4] = {0.f, 0.f, 0.f, 0.f};
#pragma unroll
    for (int it = 0; it < 2; it++) {
        int mb = z * 1024 + it * 512 + lane * 8;
        if (mb > nmax) continue;
        u16x8 cv[4];
#pragma unroll
        for (int r = 0; r < 4; r++) cv[r] = *reinterpret_cast<const u16x8*>(crow0 + (long)r * 2048 + mb);
        float4 ch[8];
        if (T > 0) {
#pragma unroll
            for (int j = 0; j < 8; j++) ch[j] = charges4[colbase + mb + j];
        }
#pragma unroll
        for (int j = 0; j < 8; j++) {
#pragma unroll
            for (int r = 0; r < 4; r++) {
                float sg = 1.f;
                if (T > 0) sg += rfx[r] * ch[j].x;
                if (T > 1) sg += rfy[r] * ch[j].y;
                if (T > 2) sg += rfz[r] * ch[j].z;
                if (T > 3) sg += rfw[r] * ch[j].w;
                float e = (mb + j <= rw0 + r) ? __expf(bf2f(cv[r][j]) * sg) : 0.f;
                S[r] += e;
            }
        }
    }
#pragma unroll
    for (int off = 32; off > 0; off >>= 1) {
#pragma unroll
        for (int r = 0; r < 4; r++) S[r] += __shfl_down(S[r], off);
    }
    if (lane == 0) {
#pragma unroll
        for (int r = 0; r < 4; r++) Lp[z * 8192 + colbase + rw0 + r] = S[r];
    }
}

// ---------------- pass B: received[m] += sum_n attn[n][m].
// Block = (batch, tile, 32-n chunk). Thread = 8-col octet x 2 n's; u16x8 compat loads;
// n-side (1/L, step*charges) preloaded to LDS; LDS-tree reduction (no serial 2-thread split).
template <int T>
__global__ __launch_bounds__(256) void k_colsum(const ushort_t* __restrict__ compat,
        const float4* __restrict__ charges4, const float* __restrict__ stepp,
        const float* __restrict__ Lp, float* __restrict__ received) {
    __shared__ float nvx[32], nvy[32], nvz[32], nvw[32], nLi[32];
    __shared__ float sums[16][136];
    int bid = blockIdx.x;
    int b = bid / 544, rem = bid % 544;
    int q = rem & 3, r = rem >> 2, ti, tj;
    tri_decode(r, ti, tj);
    int tid = threadIdx.x;
    float step = stepp[0];
    if (tid < 32) {
        int nid = b * 2048 + ti * 128 + q * 32 + tid;
        nLi[tid] = 1.0f / fmaxf(Lp[nid] + Lp[8192 + nid], 1e-30f);
        if (T > 0) {
            float4 cn = charges4[nid];
            nvx[tid] = step * cn.x;
            if (T > 1) nvy[tid] = step * cn.y;
            if (T > 2) nvz[tid] = step * cn.z;
            if (T > 3) nvw[tid] = step * cn.w;
        }
    }
    __syncthreads();
    int cg = tid & 15, ng = tid >> 4;
    int m0 = tj * 128 + cg * 8;
    long mid0 = (long)b * 2048 + m0;
    float4 cm[8];
    if (T > 0) {
#pragma unroll
        for (int j = 0; j < 8; j++) cm[j] = charges4[mid0 + j];
    }
    bool diag = (ti == tj);
    u16x8 cva[2];
    int nla[2];
#pragma unroll
    for (int t2 = 0; t2 < 2; t2++) {
        nla[t2] = q * 32 + ng + t2 * 16;
        long nid = (long)b * 2048 + ti * 128 + nla[t2];
        cva[t2] = *reinterpret_cast<const u16x8*>(compat + nid * 2048 + m0);
    }
    float acc[8] = {};
#pragma unroll
    for (int t2 = 0; t2 < 2; t2++) {
        int nloc = ng + t2 * 16;
        float Li = nLi[nloc];
        float ax = (T > 0) ? nvx[nloc] : 0.f;
        float ay = (T > 1) ? nvy[nloc] : 0.f;
        float az = (T > 2) ? nvz[nloc] : 0.f;
        float aw = (T > 3) ? nvw[nloc] : 0.f;
        int nglob = ti * 128 + nla[t2];
#pragma unroll
        for (int j = 0; j < 8; j++) {
            float sg = 1.f;
            if (T > 0) sg += ax * cm[j].x;
            if (T > 1) sg += ay * cm[j].y;
            if (T > 2) sg += az * cm[j].z;
            if (T > 3) sg += aw * cm[j].w;
            float p = __expf(bf2f(cva[t2][j]) * sg) * Li;
            if (!diag || m0 + j <= nglob) acc[j] += p;
        }
    }
#pragma unroll
    for (int j = 0; j < 8; j++) sums[ng][cg * 8 + j] = acc[j];
    __syncthreads();
    if (tid < 128) {
        float s = 0.f;
#pragma unroll
        for (int g = 0; g < 16; g++) s += sums[g][tid];
        atomicAdd(&received[b * 2048 + tj * 128 + tid], s);
    }
}

// ---------------- charge update t (writes charges4 component T-1; re-zeroes received)
template <int T>
__global__ void k_charge(float* __restrict__ received, const float* __restrict__ charge0,
                         float4* __restrict__ charges4, const float* __restrict__ decayp) {
    int i = blockIdx.x * 256 + threadIdx.x;
    if (i >= 8192) return;
    float decay = decayp[0];
    float rcv = received[i];
    float sg = 1.0f / (1.0f + __expf(1.0f - rcv));
    float prev = (T == 1) ? charge0[i] : ((const float*)&charges4[i])[T - 2];
    ((float*)&charges4[i])[T - 1] = prev * (1.f - decay * sg);
    received[i] = 0.f;
}

// ---------------- final attention + PV, self-normalizing (512 blocks, col-split waves)
__global__ __launch_bounds__(256) void k_pv(const ushort_t* __restrict__ compat,
        const float4* __restrict__ charges4, const float* __restrict__ stepp,
        const ushort_t* __restrict__ VbT, float* __restrict__ Oacc) {
    __shared__ float accL[3][64][17];
    __shared__ float ssL[4][16];
    int bid = blockIdx.x;
    int b = bid & 3, rtile = 127 - (bid >> 2);  // big tiles dispatched first
    int r0 = rtile * 16;
    int w = threadIdx.x >> 6, lane = threadIdx.x & 63;
    int l16 = lane & 15, quad = lane >> 4;
    int rowl = r0 + l16;
    int rid = b * 2048 + rowl;
    float step = stepp[0];
    float4 c4 = charges4[rid];
    float rx = step * c4.x, ry = step * c4.y, rz = step * c4.z, rw = step * c4.w;
    const ushort_t* crow = compat + (long)rid * 2048;
    f32x4 acc[4] = {};
    float Ss = 0.f;
    int colend = r0 + 16;
    for (int kc = w * 32; kc < colend; kc += 128) {
        int mk = kc + quad * 8;
        u16x8 cv = *reinterpret_cast<const u16x8*>(crow + mk);
        const float4* chp = charges4 + b * 2048 + mk;
        bf16x8 pf;
#pragma unroll
        for (int j = 0; j < 8; j++) {
            float4 ch = chp[j];
            float sg = 1.f + rx * ch.x + ry * ch.y + rz * ch.z + rw * ch.w;
            float p = (mk + j <= rowl) ? __expf(bf2f(cv[j]) * sg) : 0.f;
            Ss += p;
            pf[j] = f2bf(p);
        }
        bf16x8 vf[4];
#pragma unroll
        for (int f = 0; f < 4; f++)
            vf[f] = *reinterpret_cast<const bf16x8*>(VbT + (long)(f * 16 + l16) * 8192 + b * 2048 + mk);
#pragma unroll
        for (int f = 0; f < 4; f++)
            acc[f] = __builtin_amdgcn_mfma_f32_16x16x32_bf16(pf, vf[f], acc[f], 0, 0, 0);
    }
    Ss += __shfl_xor(Ss, 16);
    Ss += __shfl_xor(Ss, 32);
    if (quad == 0) ssL[w][l16] = Ss;
    if (w > 0) {
#pragma unroll
        for (int f = 0; f < 4; f++)
#pragma unroll
            for (int rr = 0; rr < 4; rr++)
                accL[w - 1][lane][f * 4 + rr] = acc[f][rr];
    }
    __syncthreads();
    if (w == 0) {
#pragma unroll
        for (int f = 0; f < 4; f++)
#pragma unroll
            for (int rr = 0; rr < 4; rr++)
                acc[f][rr] += accL[0][lane][f * 4 + rr] + accL[1][lane][f * 4 + rr] + accL[2][lane][f * 4 + rr];
        float Sinv[4];
#pragma unroll
        for (int rr = 0; rr < 4; rr++) {
            int idx = quad * 4 + rr;
            float st = ssL[0][idx] + ssL[1][idx] + ssL[2][idx] + ssL[3][idx];
            Sinv[rr] = 1.f / fmaxf(st, 1e-30f);
        }
#pragma unroll
        for (int f = 0; f < 4; f++)
#pragma unroll
            for (int rr = 0; rr < 4; rr++) {
                int row = r0 + quad * 4 + rr;
                Oacc[(long)(b * 2048 + row) * 64 + f * 16 + l16] = acc[f][rr] * Sinv[rr];
            }
    }
}

// ---------------- out = (Oacc @ Wo^T) * 0.1, fp32 store
__global__ __launch_bounds__(256) void k_oproj(const float* __restrict__ Oacc,
                                               const float* __restrict__ Wo,
                                               float* __restrict__ out) {
    int mt = blockIdx.x & 63, nt = blockIdx.x >> 6;
    int wave = threadIdx.x >> 6, lane = threadIdx.x & 63;
    int wm = wave >> 1, wn = wave & 1;
    int l16 = lane & 15, quad = lane >> 4;
    int row0 = mt * 128 + wm * 64;
    int col0 = nt * 128 + wn * 64;
    f32x4 acc[4][4] = {};
#pragma unroll
    for (int kc = 0; kc < 64; kc += 32) {
        int ko = kc + quad * 8;
        bf16x8 af[4], bfm[4];
#pragma unroll
        for (int f = 0; f < 4; f++) af[f] = ld8f(Oacc + (long)(row0 + f * 16 + l16) * 64 + ko);
#pragma unroll
        for (int f = 0; f < 4; f++) bfm[f] = ld8f(Wo + (long)(col0 + f * 16 + l16) * 64 + ko);
#pragma unroll
        for (int i = 0; i < 4; i++)
#pragma unroll
            for (int j = 0; j < 4; j++)
                acc[i][j] = __builtin_amdgcn_mfma_f32_16x16x32_bf16(af[i], bfm[j], acc[i][j], 0, 0, 0);
    }
#pragma unroll
    for (int i = 0; i < 4; i++)
#pragma unroll
        for (int j = 0; j < 4; j++)
#pragma unroll
            for (int rr = 0; rr < 4; rr++) {
                long rowg = row0 + i * 16 + quad * 4 + rr;
                int colg = col0 + j * 16 + l16;
                out[rowg * 1024 + colg] = acc[i][j][rr] * 0.1f;
            }
}

extern "C" void kernel_launch(void* const* d_in, const int* in_sizes, int n_in,
                              void* d_out, int out_size, void* d_ws, size_t ws_size,
                              hipStream_t stream) {
    const float* hidden = (const float*)d_in[0];
    const float* W1 = (const float*)d_in[1];
    const float* b1 = (const float*)d_in[2];
    const float* W2 = (const float*)d_in[3];
    const float* b2 = (const float*)d_in[4];
    const float* Wq = (const float*)d_in[5];
    const float* Wk = (const float*)d_in[6];
    const float* Wc = (const float*)d_in[7];
    const float* bc = (const float*)d_in[8];
    const float* Wv = (const float*)d_in[9];
    const float* Wo = (const float*)d_in[10];
    const float* stepp = (const float*)d_in[11];
    const float* decayp = (const float*)d_in[12];

    char* ws = (char*)d_ws;
    size_t off = 0;
    auto alloc = [&](size_t bytes) {
        void* p = ws + off;
        off += (bytes + 255) & ~(size_t)255;
        return p;
    };
    ushort_t* compat = (ushort_t*)alloc(8192UL * 2048 * 2);  // 32 MiB bf16
    ushort_t* Hb = (ushort_t*)alloc(8192UL * 1024 * 2);      // 16 MiB bf16 hidden
    ushort_t* Wcat = (ushort_t*)alloc(128UL * 1024 * 2);     // W1;Wv bf16
    float* Ff = (float*)alloc(8192UL * 64 * 4);              // 2 MiB
    ushort_t* Qb = (ushort_t*)alloc(8192UL * 64 * 2);
    ushort_t* Kb = (ushort_t*)alloc(8192UL * 64 * 2);
    ushort_t* VbT = (ushort_t*)alloc(64UL * 8192 * 2);
    float* Oacc = (float*)alloc(8192UL * 64 * 4);
    float4* charges4 = (float4*)alloc(8192UL * 16);
    float* charge0 = (float*)alloc(8192UL * 4);
    float* Lp = (float*)alloc(2UL * 8192 * 4);
    float* received = (float*)alloc(8192UL * 4);
    (void)ws_size; (void)in_sizes; (void)n_in; (void)out_size;

    k_cvt<<<4096, 256, 0, stream>>>(hidden, Hb, 8192 * 1024 / 8);
    k_cvt<<<32, 256, 0, stream>>>(W1, Wcat, 64 * 1024 / 8);
    k_cvt<<<32, 256, 0, stream>>>(Wv, Wcat + 64 * 1024, 64 * 1024 / 8);
    k_fv<<<512, 256, 0, stream>>>(Hb, Wcat, Ff, VbT);
    k_feat<<<256, 256, 0, stream>>>(Ff, b1, W2, b2, Wq, Wk, Wc, bc, Qb, Kb, charge0, received);
    k_compat<<<544, 256, 0, stream>>>(Qb, Kb, compat);

    k_rowstats<0><<<1024, 256, 0, stream>>>(compat, charges4, stepp, Lp);
    k_colsum<0><<<2176, 256, 0, stream>>>(compat, charges4, stepp, Lp, received);
    k_charge<1><<<32, 256, 0, stream>>>(received, charge0, charges4, decayp);

    k_rowstats<1><<<1024, 256, 0, stream>>>(compat, charges4, stepp, Lp);
    k_colsum<1><<<2176, 256, 0, stream>>>(compat, charges4, stepp, Lp, received);
    k_charge<2><<<32, 256, 0, stream>>>(received, charge0, charges4, decayp);

    k_rowstats<2><<<1024, 256, 0, stream>>>(compat, charges4, stepp, Lp);
    k_colsum<2><<<2176, 256, 0, stream>>>(compat, charges4, stepp, Lp, received);
    k_charge<3><<<32, 256, 0, stream>>>(received, charge0, charges4, decayp);

    k_rowstats<3><<<1024, 256, 0, stream>>>(compat, charges4, stepp, Lp);
    k_colsum<3><<<2176, 256, 0, stream>>>(compat, charges4, stepp, Lp, received);
    k_charge<4><<<32, 256, 0, stream>>>(received, charge0, charges4, decayp);

    k_pv<<<512, 256, 0, stream>>>(compat, charges4, stepp, VbT, Oacc);
    k_oproj<<<512, 256, 0, stream>>>(Oacc, Wo, (float*)d_out);
}

// Round 10
// 277.479 us; speedup vs baseline: 1.2681x; 1.0521x over previous
//
#include <hip/hip_runtime.h>
#include <hip/hip_bf16.h>

typedef unsigned short ushort_t;
typedef short bf16x8 __attribute__((ext_vector_type(8)));
typedef ushort_t u16x8 __attribute__((ext_vector_type(8)));
typedef float f32x4 __attribute__((ext_vector_type(4)));

#define DEV static __device__ __forceinline__

DEV float bf2f(ushort_t u) { unsigned v = ((unsigned)u) << 16; float f; __builtin_memcpy(&f, &v, 4); return f; }
DEV short f2bf(float x) { __hip_bfloat16 h = __float2bfloat16(x); short s; __builtin_memcpy(&s, &h, 2); return s; }
DEV float sigm(float x) { return 1.0f / (1.0f + __expf(-x)); }

DEV bf16x8 cvt8(float4 a0, float4 a1) {
    bf16x8 t;
    t[0] = f2bf(a0.x); t[1] = f2bf(a0.y); t[2] = f2bf(a0.z); t[3] = f2bf(a0.w);
    t[4] = f2bf(a1.x); t[5] = f2bf(a1.y); t[6] = f2bf(a1.z); t[7] = f2bf(a1.w);
    return t;
}
DEV bf16x8 ld8f(const float* __restrict__ p) {
    return cvt8(*reinterpret_cast<const float4*>(p), *reinterpret_cast<const float4*>(p + 4));
}

// ---------------- K0: fp32 -> bf16 for hidden, W1, Wv (one launch; 8 elems/thread)
__global__ void k_cvt(const float* __restrict__ h, const float* __restrict__ W1,
                      const float* __restrict__ Wv, ushort_t* __restrict__ Hb,
                      ushort_t* __restrict__ Wcat) {
    long i = (long)blockIdx.x * 256 + threadIdx.x;
    const float* src;
    ushort_t* dst;
    if (i < 1048576) { src = h + i * 8; dst = Hb + i * 8; }
    else if (i < 1056768) { long j = i - 1048576; src = W1 + j * 8; dst = Wcat + j * 8; }
    else { long j = i - 1056768; src = Wv + j * 8; dst = Wcat + 65536 + j * 8; }
    const float4* p = reinterpret_cast<const float4*>(src);
    *reinterpret_cast<bf16x8*>(dst) = cvt8(p[0], p[1]);
}

// ---------------- K1: Ff[8192][64] = Hb@W1^T (fp32), VbT[64][8192] = (Hb@Wv^T)^T bf16
__global__ __launch_bounds__(256) void k_fv(const ushort_t* __restrict__ Hb,
        const ushort_t* __restrict__ Wcat,
        float* __restrict__ Ff, ushort_t* __restrict__ VbT) {
    int m0 = blockIdx.x * 16;
    int wave = threadIdx.x >> 6, lane = threadIdx.x & 63;
    int l16 = lane & 15, quad = lane >> 4;
    int cb = (wave & 1) * 32;
    int brow_off = (wave < 2) ? 0 : 64;   // rows 0-63 = W1, 64-127 = Wv
    f32x4 acc[2] = {};
    const ushort_t* arow = Hb + (long)(m0 + l16) * 1024;
    const ushort_t* brow0 = Wcat + (long)(brow_off + cb + l16) * 1024;
    const ushort_t* brow1 = Wcat + (long)(brow_off + cb + 16 + l16) * 1024;
    for (int kc = 0; kc < 1024; kc += 128) {
        bf16x8 a4[4], b04[4], b14[4];
#pragma unroll
        for (int u = 0; u < 4; u++) {
            int ko = kc + u * 32 + quad * 8;
            a4[u] = *reinterpret_cast<const bf16x8*>(arow + ko);
            b04[u] = *reinterpret_cast<const bf16x8*>(brow0 + ko);
            b14[u] = *reinterpret_cast<const bf16x8*>(brow1 + ko);
        }
#pragma unroll
        for (int u = 0; u < 4; u++) {
            acc[0] = __builtin_amdgcn_mfma_f32_16x16x32_bf16(a4[u], b04[u], acc[0], 0, 0, 0);
            acc[1] = __builtin_amdgcn_mfma_f32_16x16x32_bf16(a4[u], b14[u], acc[1], 0, 0, 0);
        }
    }
    bool isV = (wave >= 2);
#pragma unroll
    for (int c = 0; c < 2; c++)
#pragma unroll
        for (int rr = 0; rr < 4; rr++) {
            int row = m0 + quad * 4 + rr;
            int col = cb + c * 16 + l16;
            float v = acc[c][rr];
            if (!isV) Ff[row * 64 + col] = v;
            else VbT[(long)col * 8192 + row] = (ushort_t)f2bf(v);
        }
}

// ---------------- K2: gelu -> features -> Q,K,charge0; zero received. 256 blocks x 32 rows.
__global__ __launch_bounds__(256) void k_feat(const float* __restrict__ Ff,
        const float* __restrict__ b1, const float* __restrict__ W2, const float* __restrict__ b2,
        const float* __restrict__ Wq, const float* __restrict__ Wk,
        const float* __restrict__ Wc, const float* __restrict__ bc,
        ushort_t* __restrict__ Qb, ushort_t* __restrict__ Kb,
        float* __restrict__ charge0, float* __restrict__ received) {
    __shared__ float w2L[28 * 65], wqL[64 * 29], wkL[64 * 29], wcL[28], b2L[28];
    __shared__ float fL[4][64], featL[4][28];
    int tid = threadIdx.x;
    for (int i = tid; i < 28 * 64; i += 256) w2L[(i >> 6) * 65 + (i & 63)] = W2[i];
    for (int i = tid; i < 64 * 28; i += 256) {
        int r = i / 28, c = i - r * 28;
        wqL[r * 29 + c] = Wq[i];
        wkL[r * 29 + c] = Wk[i];
    }
    if (tid < 28) { wcL[tid] = Wc[tid]; b2L[tid] = b2[tid]; }
    __syncthreads();
    int w = tid >> 6, lane = tid & 63;
    float b1v = b1[lane];
    float bcv = bc[0];
    for (int it = 0; it < 8; it++) {
        int row = blockIdx.x * 32 + it * 4 + w;
        float x = Ff[row * 64 + lane] + b1v;
        fL[w][lane] = 0.5f * x * (1.0f + erff(x * 0.70710678118654752f));
        __syncthreads();
        if (lane < 28) {
            float s = b2L[lane];
#pragma unroll
            for (int j = 0; j < 64; j++) s += fL[w][j] * w2L[lane * 65 + j];
            featL[w][lane] = sigm(s);
        }
        __syncthreads();
        float q = 0.f, k = 0.f;
#pragma unroll
        for (int i = 0; i < 28; i++) {
            float fv = featL[w][i];
            q += fv * wqL[lane * 29 + i];
            k += fv * wkL[lane * 29 + i];
        }
        Qb[row * 64 + lane] = (ushort_t)f2bf(q * 0.125f);  // fold 1/sqrt(64)
        Kb[row * 64 + lane] = (ushort_t)f2bf(k);
        if (lane == 0) {
            float c = bcv;
#pragma unroll
            for (int i = 0; i < 28; i++) c += featL[w][i] * wcL[i];
            charge0[row] = sigm(c);
            received[row] = 0.f;
        }
        __syncthreads();
    }
}

DEV void tri_decode(int r, int& ti, int& tj) {
    int t = (int)((sqrtf(8.f * (float)r + 1.f) - 1.f) * 0.5f);
    while ((t + 1) * (t + 2) / 2 <= r) t++;
    while (t * (t + 1) / 2 > r) t--;
    ti = t;
    tj = r - t * (t + 1) / 2;
}

// ---------------- K3: compat[(b*2048+n)][m] = (Q/8)·K, causal 128x128 tiles, bf16 store
__global__ __launch_bounds__(256) void k_compat(const ushort_t* __restrict__ Qb,
                                                const ushort_t* __restrict__ Kb,
                                                ushort_t* __restrict__ compat) {
    int bid = blockIdx.x;
    int b = bid / 136, r = bid % 136, ti, tj;
    tri_decode(r, ti, tj);
    int wave = threadIdx.x >> 6, lane = threadIdx.x & 63;
    int l16 = lane & 15, quad = lane >> 4;
    int rbase = b * 2048 + ti * 128 + wave * 32;
    int cbase = b * 2048 + tj * 128;
    f32x4 acc[2][8] = {};
#pragma unroll
    for (int kc = 0; kc < 64; kc += 32) {
        int ko = kc + quad * 8;
        bf16x8 af[2], bf[8];
#pragma unroll
        for (int f = 0; f < 2; f++) af[f] = *reinterpret_cast<const bf16x8*>(Qb + (long)(rbase + f * 16 + l16) * 64 + ko);
#pragma unroll
        for (int f = 0; f < 8; f++) bf[f] = *reinterpret_cast<const bf16x8*>(Kb + (long)(cbase + f * 16 + l16) * 64 + ko);
#pragma unroll
        for (int i = 0; i < 2; i++)
#pragma unroll
            for (int j = 0; j < 8; j++)
                acc[i][j] = __builtin_amdgcn_mfma_f32_16x16x32_bf16(af[i], bf[j], acc[i][j], 0, 0, 0);
    }
    int colt = tj * 128;
#pragma unroll
    for (int i = 0; i < 2; i++)
#pragma unroll
        for (int j = 0; j < 8; j++)
#pragma unroll
            for (int rr = 0; rr < 4; rr++) {
                long rowg = rbase + i * 16 + quad * 4 + rr;
                int col = colt + j * 16 + l16;
                compat[rowg * 2048 + col] = (ushort_t)f2bf(acc[i][j][rr]);
            }
}

// ---------------- pass A: Lrow[n] = sum_m<=n exp(compat*sigma), written directly.
// Block = 16 rows; wave = one 512-col strip; lane keeps its 8 col-charges in registers
// across all 16 rows (amortization fix for R9's 0.25 loads/elem).
template <int T>
__global__ __launch_bounds__(256) void k_rowstats(const ushort_t* __restrict__ compat,
        const float4* __restrict__ charges4, const float* __restrict__ stepp,
        float* __restrict__ Lrow) {
    __shared__ float lsum[4][16];
    int bid = blockIdx.x;
    int b = bid & 3, rt = 127 - (bid >> 2);   // big tiles first
    int w = threadIdx.x >> 6, lane = threadIdx.x & 63;
    int r0 = rt * 16;
    int colbase = b * 2048;
    int mb = w * 512 + lane * 8;
    float step = stepp[0];
    float S[16];
#pragma unroll
    for (int i = 0; i < 16; i++) S[i] = 0.f;
    if (mb <= r0 + 15) {
        float chx[8] = {}, chy[8] = {}, chz[8] = {}, chw[8] = {};
        if (T > 0) {
#pragma unroll
            for (int j = 0; j < 8; j++) {
                float4 c = charges4[colbase + mb + j];
                chx[j] = c.x;
                if (T > 1) chy[j] = c.y;
                if (T > 2) chz[j] = c.z;
                if (T > 3) chw[j] = c.w;
            }
        }
        const ushort_t* cbase = compat + (long)(colbase + r0) * 2048 + mb;
        for (int rb = 0; rb < 4; rb++) {
            int rr0 = r0 + rb * 4;
            if (mb > rr0 + 3) continue;
            u16x8 cv[4];
#pragma unroll
            for (int rr = 0; rr < 4; rr++)
                cv[rr] = *reinterpret_cast<const u16x8*>(cbase + (long)(rb * 4 + rr) * 2048);
            float rfx[4] = {}, rfy[4] = {}, rfz[4] = {}, rfw[4] = {};
            if (T > 0) {
#pragma unroll
                for (int rr = 0; rr < 4; rr++) {
                    float4 c4 = charges4[colbase + rr0 + rr];
                    rfx[rr] = step * c4.x;
                    if (T > 1) rfy[rr] = step * c4.y;
                    if (T > 2) rfz[rr] = step * c4.z;
                    if (T > 3) rfw[rr] = step * c4.w;
                }
            }
#pragma unroll
            for (int rr = 0; rr < 4; rr++) {
                int n = rr0 + rr;
#pragma unroll
                for (int j = 0; j < 8; j++) {
                    float sg = 1.f;
                    if (T > 0) sg += rfx[rr] * chx[j];
                    if (T > 1) sg += rfy[rr] * chy[j];
                    if (T > 2) sg += rfz[rr] * chz[j];
                    if (T > 3) sg += rfw[rr] * chw[j];
                    float e = (mb + j <= n) ? __expf(bf2f(cv[rr][j]) * sg) : 0.f;
                    S[rb * 4 + rr] += e;
                }
            }
        }
    }
#pragma unroll
    for (int off = 32; off > 0; off >>= 1) {
#pragma unroll
        for (int i = 0; i < 16; i++) S[i] += __shfl_down(S[i], off);
    }
    if (lane == 0) {
#pragma unroll
        for (int i = 0; i < 16; i++) lsum[w][i] = S[i];
    }
    __syncthreads();
    if (threadIdx.x < 16) {
        float s = lsum[0][threadIdx.x] + lsum[1][threadIdx.x] + lsum[2][threadIdx.x] + lsum[3][threadIdx.x];
        Lrow[colbase + r0 + threadIdx.x] = fmaxf(s, 1e-30f);
    }
}

// ---------------- pass B: received[m] += sum_n attn[n][m]. Block = full 128x128 tile;
// n-side (1/L, step*charges) staged in LDS once; m-side charges in registers across
// the whole 8-step n-loop; one syncthreads + LDS-tree + one atomic per column.
template <int T>
__global__ __launch_bounds__(256) void k_colsum(const ushort_t* __restrict__ compat,
        const float4* __restrict__ charges4, const float* __restrict__ stepp,
        const float* __restrict__ Lrow, float* __restrict__ received) {
    __shared__ float nLi[128], nvx[128], nvy[128], nvz[128], nvw[128];
    __shared__ float sums[16][136];
    int bid = blockIdx.x;
    int b = bid & 3, r = bid >> 2, ti, tj;
    tri_decode(r, ti, tj);
    int tid = threadIdx.x;
    float step = stepp[0];
    if (tid < 128) {
        int nid = b * 2048 + ti * 128 + tid;
        nLi[tid] = 1.0f / Lrow[nid];
        if (T > 0) {
            float4 cn = charges4[nid];
            nvx[tid] = step * cn.x;
            if (T > 1) nvy[tid] = step * cn.y;
            if (T > 2) nvz[tid] = step * cn.z;
            if (T > 3) nvw[tid] = step * cn.w;
        }
    }
    __syncthreads();
    int cg = tid & 15, ng = tid >> 4;
    int m0 = tj * 128 + cg * 8;
    float cmx[8] = {}, cmy[8] = {}, cmz[8] = {}, cmw[8] = {};
    if (T > 0) {
#pragma unroll
        for (int j = 0; j < 8; j++) {
            float4 c = charges4[b * 2048 + m0 + j];
            cmx[j] = c.x;
            if (T > 1) cmy[j] = c.y;
            if (T > 2) cmz[j] = c.z;
            if (T > 3) cmw[j] = c.w;
        }
    }
    bool diag = (ti == tj);
    const ushort_t* cbase = compat + (long)(b * 2048 + ti * 128) * 2048 + m0;
    float acc[8] = {};
    for (int nb = 0; nb < 8; nb++) {
        int nloc = nb * 16 + ng;
        u16x8 cv = *reinterpret_cast<const u16x8*>(cbase + (long)nloc * 2048);
        float Li = nLi[nloc];
        float ax = (T > 0) ? nvx[nloc] : 0.f;
        float ay = (T > 1) ? nvy[nloc] : 0.f;
        float az = (T > 2) ? nvz[nloc] : 0.f;
        float aw = (T > 3) ? nvw[nloc] : 0.f;
        int nglob = ti * 128 + nloc;
#pragma unroll
        for (int j = 0; j < 8; j++) {
            float sg = 1.f;
            if (T > 0) sg += ax * cmx[j];
            if (T > 1) sg += ay * cmy[j];
            if (T > 2) sg += az * cmz[j];
            if (T > 3) sg += aw * cmw[j];
            float p = __expf(bf2f(cv[j]) * sg) * Li;
            if (!diag || m0 + j <= nglob) acc[j] += p;
        }
    }
#pragma unroll
    for (int j = 0; j < 8; j++) sums[ng][cg * 8 + j] = acc[j];
    __syncthreads();
    if (tid < 128) {
        float s = 0.f;
#pragma unroll
        for (int g = 0; g < 16; g++) s += sums[g][tid];
        atomicAdd(&received[b * 2048 + tj * 128 + tid], s);
    }
}

// ---------------- charge update t (writes charges4 component T-1; re-zeroes received)
template <int T>
__global__ void k_charge(float* __restrict__ received, const float* __restrict__ charge0,
                         float4* __restrict__ charges4, const float* __restrict__ decayp) {
    int i = blockIdx.x * 256 + threadIdx.x;
    if (i >= 8192) return;
    float decay = decayp[0];
    float rcv = received[i];
    float sg = 1.0f / (1.0f + __expf(1.0f - rcv));
    float prev = (T == 1) ? charge0[i] : ((const float*)&charges4[i])[T - 2];
    ((float*)&charges4[i])[T - 1] = prev * (1.f - decay * sg);
    received[i] = 0.f;
}

// ---------------- final attention + PV, self-normalizing (512 blocks, col-split waves)
__global__ __launch_bounds__(256) void k_pv(const ushort_t* __restrict__ compat,
        const float4* __restrict__ charges4, const float* __restrict__ stepp,
        const ushort_t* __restrict__ VbT, float* __restrict__ Oacc) {
    __shared__ float accL[3][64][17];
    __shared__ float ssL[4][16];
    int bid = blockIdx.x;
    int b = bid & 3, rtile = 127 - (bid >> 2);  // big tiles dispatched first
    int r0 = rtile * 16;
    int w = threadIdx.x >> 6, lane = threadIdx.x & 63;
    int l16 = lane & 15, quad = lane >> 4;
    int rowl = r0 + l16;
    int rid = b * 2048 + rowl;
    float step = stepp[0];
    float4 c4 = charges4[rid];
    float rx = step * c4.x, ry = step * c4.y, rz = step * c4.z, rw = step * c4.w;
    const ushort_t* crow = compat + (long)rid * 2048;
    f32x4 acc[4] = {};
    float Ss = 0.f;
    int colend = r0 + 16;
    for (int kc = w * 32; kc < colend; kc += 128) {
        int mk = kc + quad * 8;
        u16x8 cv = *reinterpret_cast<const u16x8*>(crow + mk);
        const float4* chp = charges4 + b * 2048 + mk;
        bf16x8 pf;
#pragma unroll
        for (int j = 0; j < 8; j++) {
            float4 ch = chp[j];
            float sg = 1.f + rx * ch.x + ry * ch.y + rz * ch.z + rw * ch.w;
            float p = (mk + j <= rowl) ? __expf(bf2f(cv[j]) * sg) : 0.f;
            Ss += p;
            pf[j] = f2bf(p);
        }
        bf16x8 vf[4];
#pragma unroll
        for (int f = 0; f < 4; f++)
            vf[f] = *reinterpret_cast<const bf16x8*>(VbT + (long)(f * 16 + l16) * 8192 + b * 2048 + mk);
#pragma unroll
        for (int f = 0; f < 4; f++)
            acc[f] = __builtin_amdgcn_mfma_f32_16x16x32_bf16(pf, vf[f], acc[f], 0, 0, 0);
    }
    Ss += __shfl_xor(Ss, 16);
    Ss += __shfl_xor(Ss, 32);
    if (quad == 0) ssL[w][l16] = Ss;
    if (w > 0) {
#pragma unroll
        for (int f = 0; f < 4; f++)
#pragma unroll
            for (int rr = 0; rr < 4; rr++)
                accL[w - 1][lane][f * 4 + rr] = acc[f][rr];
    }
    __syncthreads();
    if (w == 0) {
#pragma unroll
        for (int f = 0; f < 4; f++)
#pragma unroll
            for (int rr = 0; rr < 4; rr++)
                acc[f][rr] += accL[0][lane][f * 4 + rr] + accL[1][lane][f * 4 + rr] + accL[2][lane][f * 4 + rr];
        float Sinv[4];
#pragma unroll
        for (int rr = 0; rr < 4; rr++) {
            int idx = quad * 4 + rr;
            float st = ssL[0][idx] + ssL[1][idx] + ssL[2][idx] + ssL[3][idx];
            Sinv[rr] = 1.f / fmaxf(st, 1e-30f);
        }
#pragma unroll
        for (int f = 0; f < 4; f++)
#pragma unroll
            for (int rr = 0; rr < 4; rr++) {
                int row = r0 + quad * 4 + rr;
                Oacc[(long)(b * 2048 + row) * 64 + f * 16 + l16] = acc[f][rr] * Sinv[rr];
            }
    }
}

// ---------------- out = (Oacc @ Wo^T) * 0.1, fp32 store
__global__ __launch_bounds__(256) void k_oproj(const float* __restrict__ Oacc,
                                               const float* __restrict__ Wo,
                                               float* __restrict__ out) {
    int mt = blockIdx.x & 63, nt = blockIdx.x >> 6;
    int wave = threadIdx.x >> 6, lane = threadIdx.x & 63;
    int wm = wave >> 1, wn = wave & 1;
    int l16 = lane & 15, quad = lane >> 4;
    int row0 = mt * 128 + wm * 64;
    int col0 = nt * 128 + wn * 64;
    f32x4 acc[4][4] = {};
#pragma unroll
    for (int kc = 0; kc < 64; kc += 32) {
        int ko = kc + quad * 8;
        bf16x8 af[4], bfm[4];
#pragma unroll
        for (int f = 0; f < 4; f++) af[f] = ld8f(Oacc + (long)(row0 + f * 16 + l16) * 64 + ko);
#pragma unroll
        for (int f = 0; f < 4; f++) bfm[f] = ld8f(Wo + (long)(col0 + f * 16 + l16) * 64 + ko);
#pragma unroll
        for (int i = 0; i < 4; i++)
#pragma unroll
            for (int j = 0; j < 4; j++)
                acc[i][j] = __builtin_amdgcn_mfma_f32_16x16x32_bf16(af[i], bfm[j], acc[i][j], 0, 0, 0);
    }
#pragma unroll
    for (int i = 0; i < 4; i++)
#pragma unroll
        for (int j = 0; j < 4; j++)
#pragma unroll
            for (int rr = 0; rr < 4; rr++) {
                long rowg = row0 + i * 16 + quad * 4 + rr;
                int colg = col0 + j * 16 + l16;
                out[rowg * 1024 + colg] = acc[i][j][rr] * 0.1f;
            }
}

extern "C" void kernel_launch(void* const* d_in, const int* in_sizes, int n_in,
                              void* d_out, int out_size, void* d_ws, size_t ws_size,
                              hipStream_t stream) {
    const float* hidden = (const float*)d_in[0];
    const float* W1 = (const float*)d_in[1];
    const float* b1 = (const float*)d_in[2];
    const float* W2 = (const float*)d_in[3];
    const float* b2 = (const float*)d_in[4];
    const float* Wq = (const float*)d_in[5];
    const float* Wk = (const float*)d_in[6];
    const float* Wc = (const float*)d_in[7];
    const float* bc = (const float*)d_in[8];
    const float* Wv = (const float*)d_in[9];
    const float* Wo = (const float*)d_in[10];
    const float* stepp = (const float*)d_in[11];
    const float* decayp = (const float*)d_in[12];

    char* ws = (char*)d_ws;
    size_t off = 0;
    auto alloc = [&](size_t bytes) {
        void* p = ws + off;
        off += (bytes + 255) & ~(size_t)255;
        return p;
    };
    ushort_t* compat = (ushort_t*)alloc(8192UL * 2048 * 2);  // 32 MiB bf16
    ushort_t* Hb = (ushort_t*)alloc(8192UL * 1024 * 2);      // 16 MiB bf16 hidden
    ushort_t* Wcat = (ushort_t*)alloc(128UL * 1024 * 2);     // W1;Wv bf16
    float* Ff = (float*)alloc(8192UL * 64 * 4);              // 2 MiB
    ushort_t* Qb = (ushort_t*)alloc(8192UL * 64 * 2);
    ushort_t* Kb = (ushort_t*)alloc(8192UL * 64 * 2);
    ushort_t* VbT = (ushort_t*)alloc(64UL * 8192 * 2);
    float* Oacc = (float*)alloc(8192UL * 64 * 4);
    float4* charges4 = (float4*)alloc(8192UL * 16);
    float* charge0 = (float*)alloc(8192UL * 4);
    float* Lrow = (float*)alloc(8192UL * 4);
    float* received = (float*)alloc(8192UL * 4);
    (void)ws_size; (void)in_sizes; (void)n_in; (void)out_size;

    k_cvt<<<4160, 256, 0, stream>>>(hidden, W1, Wv, Hb, Wcat);
    k_fv<<<512, 256, 0, stream>>>(Hb, Wcat, Ff, VbT);
    k_feat<<<256, 256, 0, stream>>>(Ff, b1, W2, b2, Wq, Wk, Wc, bc, Qb, Kb, charge0, received);
    k_compat<<<544, 256, 0, stream>>>(Qb, Kb, compat);

    k_rowstats<0><<<512, 256, 0, stream>>>(compat, charges4, stepp, Lrow);
    k_colsum<0><<<544, 256, 0, stream>>>(compat, charges4, stepp, Lrow, received);
    k_charge<1><<<32, 256, 0, stream>>>(received, charge0, charges4, decayp);

    k_rowstats<1><<<512, 256, 0, stream>>>(compat, charges4, stepp, Lrow);
    k_colsum<1><<<544, 256, 0, stream>>>(compat, charges4, stepp, Lrow, received);
    k_charge<2><<<32, 256, 0, stream>>>(received, charge0, charges4, decayp);

    k_rowstats<2><<<512, 256, 0, stream>>>(compat, charges4, stepp, Lrow);
    k_colsum<2><<<544, 256, 0, stream>>>(compat, charges4, stepp, Lrow, received);
    k_charge<3><<<32, 256, 0, stream>>>(received, charge0, charges4, decayp);

    k_rowstats<3><<<512, 256, 0, stream>>>(compat, charges4, stepp, Lrow);
    k_colsum<3><<<544, 256, 0, stream>>>(compat, charges4, stepp, Lrow, received);
    k_charge<4><<<32, 256, 0, stream>>>(received, charge0, charges4, decayp);

    k_pv<<<512, 256, 0, stream>>>(compat, charges4, stepp, VbT, Oacc);
    k_oproj<<<512, 256, 0, stream>>>(Oacc, Wo, (float*)d_out);
}